// Round 6
// baseline (347.205 us; speedup 1.0000x reference)
//
#include <hip/hip_runtime.h>

#define N_NODES 100000
#define N_EDGES 1600000
#define ET (N_EDGES + N_NODES)
#define NEG_SLOPE 0.2f

// bucket sort params
#define BSHIFT 9
#define BW 512                                  // nodes per bucket
#define NBUCK ((N_NODES + BW - 1) / BW)         // 196
#define BCAP 10240
#define BINCH 2048                              // edges per bin block

typedef unsigned short u16;
typedef unsigned int u32;

__device__ __forceinline__ float bf2f(u16 v) {
    return __uint_as_float(((u32)v) << 16);
}
__device__ __forceinline__ u16 f2bf(float f) {
    u32 u = __float_as_uint(f);
    u32 r = (u + 0x7FFFu + ((u >> 16) & 1u)) >> 16;  // RNE
    return (u16)r;
}
__device__ __forceinline__ float lrelu(float x) { return x > 0.f ? x : NEG_SLOPE * x; }
__device__ __forceinline__ float ldf(const void* p, int i, int bf) {
    return bf ? bf2f(((const u16*)p)[i]) : ((const float*)p)[i];
}
__device__ __forceinline__ int get_dst(const int* __restrict__ ei, int e, int ei64) {
    if (e < N_EDGES) return ei64 ? ei[2 * (N_EDGES + e)] : ei[N_EDGES + e];
    return e - N_EDGES;
}
__device__ __forceinline__ int get_src(const int* __restrict__ ei, int e, int ei64) {
    if (e < N_EDGES) return ei64 ? ei[2 * e] : ei[e];
    return e - N_EDGES;
}

// 8 bf16-channel FMA from one uint4 (16 B of an h row)
__device__ __forceinline__ void fma8(float wt, uint4 qv, float (&acc)[8]) {
    acc[0] = fmaf(wt, __uint_as_float(qv.x << 16), acc[0]);
    acc[1] = fmaf(wt, __uint_as_float(qv.x & 0xFFFF0000u), acc[1]);
    acc[2] = fmaf(wt, __uint_as_float(qv.y << 16), acc[2]);
    acc[3] = fmaf(wt, __uint_as_float(qv.y & 0xFFFF0000u), acc[3]);
    acc[4] = fmaf(wt, __uint_as_float(qv.z << 16), acc[4]);
    acc[5] = fmaf(wt, __uint_as_float(qv.z & 0xFFFF0000u), acc[5]);
    acc[6] = fmaf(wt, __uint_as_float(qv.w << 16), acc[6]);
    acc[7] = fmaf(wt, __uint_as_float(qv.w & 0xFFFF0000u), acc[7]);
}

// ---------------------------------------------------------------------------
// Detect input storage + zero bcnt (memset dispatch folded in).
// ---------------------------------------------------------------------------
__global__ void detect_kernel(const u32* __restrict__ x32, const int* __restrict__ ei,
                              int* __restrict__ flags, int* __restrict__ bcnt) {
    int lane = threadIdx.x;  // 64
    for (int i = lane; i < 256; i += 64) bcnt[i] = 0;
    u32 e = (x32[lane] >> 7) & 0xFFu;
    int ok = (e >= 96u && e <= 143u) ? 1 : 0;
    int cnt = (int)__popcll(__ballot(ok));
    int nz = (ei[2 * lane + 1] != 0) + (ei[2 * (lane + 64) + 1] != 0);
    #pragma unroll
    for (int off = 32; off > 0; off >>= 1) nz += __shfl_xor(nz, off);
    if (lane == 0) { flags[0] = (cnt >= 48) ? 1 : 0; flags[1] = (nz == 0) ? 1 : 0; }
}

// ---------------------------------------------------------------------------
// Pass 1: bin edges by dst>>9 into 196 buckets; code = (dst&511)<<17 | src.
// ---------------------------------------------------------------------------
__global__ __launch_bounds__(256) void bin_kernel(
    const int* __restrict__ ei, const int* __restrict__ flags,
    int* __restrict__ bcnt, u32* __restrict__ bbuf)
{
    __shared__ int hist[NBUCK];
    const int t = threadIdx.x;
    const int base = blockIdx.x * BINCH;
    const int ei64 = flags[1];
    for (int i = t; i < NBUCK; i += 256) hist[i] = 0;
    __syncthreads();
    for (int i = t; i < BINCH; i += 256) {
        int e = base + i;
        if (e >= ET) break;
        int d = get_dst(ei, e, ei64);
        atomicAdd(&hist[d >> BSHIFT], 1);
    }
    __syncthreads();
    for (int i = t; i < NBUCK; i += 256) {
        int c = hist[i];
        hist[i] = (c > 0) ? atomicAdd(&bcnt[i], c) : 0;
    }
    __syncthreads();
    for (int i = t; i < BINCH; i += 256) {
        int e = base + i;
        if (e >= ET) break;
        int d = get_dst(ei, e, ei64);
        int s = get_src(ei, e, ei64);
        int b = d >> BSHIFT;
        int pos = atomicAdd(&hist[b], 1);
        if (pos < BCAP)
            bbuf[(size_t)b * BCAP + pos] = ((u32)(d & (BW - 1)) << 17) | (u32)s;
    }
}

// exclusive scan of clamped bucket counts -> bbase[NBUCK+1]
__global__ __launch_bounds__(256) void bscan_kernel(
    const int* __restrict__ bcnt, int* __restrict__ bbase)
{
    __shared__ int sd[256];
    int t = threadIdx.x;
    int v = (t < NBUCK) ? min(bcnt[t], BCAP) : 0;
    sd[t] = v;
    __syncthreads();
    for (int off = 1; off < 256; off <<= 1) {
        int x = (t >= off) ? sd[t - off] : 0;
        __syncthreads();
        sd[t] += x;
        __syncthreads();
    }
    if (t < NBUCK) bbase[t] = sd[t] - v;
    if (t == NBUCK - 1) bbase[NBUCK] = sd[t];
}

// ---------------------------------------------------------------------------
// Pass 2: one block (1024 threads) per bucket -> rowptr + dst-sorted ssrc.
// ---------------------------------------------------------------------------
__global__ __launch_bounds__(1024) void scatter_kernel(
    const int* __restrict__ bcnt, const int* __restrict__ bbase,
    const u32* __restrict__ bbuf, int* __restrict__ rowptr, int* __restrict__ ssrc)
{
    __shared__ int hist[BW];
    __shared__ int cur[BW];
    __shared__ int wtot[4];
    __shared__ int lds_s[BCAP];
    const int t = threadIdx.x;
    const int b = blockIdx.x;
    const int cnt = min(bcnt[b], BCAP);
    const int base = bbase[b];
    const u32* mybuf = bbuf + (size_t)b * BCAP;

    if (t < BW) hist[t] = 0;
    __syncthreads();
    for (int i = t; i < cnt; i += 1024) atomicAdd(&hist[(int)(mybuf[i] >> 17)], 1);
    __syncthreads();
    int a0 = 0, a1 = 0, s = 0, v = 0;
    const int lane = t & 63, wid = t >> 6;
    if (t < 256) {
        a0 = hist[2 * t]; a1 = hist[2 * t + 1];
        s = a0 + a1;
        v = s;
        #pragma unroll
        for (int off = 1; off < 64; off <<= 1) {
            int n = __shfl_up(v, off);
            if (lane >= off) v += n;
        }
        if (lane == 63) wtot[wid] = v;
    }
    __syncthreads();
    if (t == 0) {
        int acc = 0;
        #pragma unroll
        for (int w = 0; w < 4; ++w) { int tmp = wtot[w]; wtot[w] = acc; acc += tmp; }
    }
    __syncthreads();
    if (t < 256) {
        int excl = v + wtot[wid] - s;
        cur[2 * t] = excl;
        cur[2 * t + 1] = excl + a0;
    }
    __syncthreads();
    if (t < BW) {
        int g = b * BW + t;
        if (g < N_NODES) rowptr[g] = base + cur[t];
    }
    if (b == NBUCK - 1 && t == 0) rowptr[N_NODES] = bbase[NBUCK];
    __syncthreads();
    for (int i = t; i < cnt; i += 1024) {
        u32 code = mybuf[i];
        int pos = atomicAdd(&cur[(int)(code >> 17)], 1);
        lds_s[pos] = (int)(code & 0x1FFFFu);
    }
    __syncthreads();
    for (int i = t; i < cnt; i += 1024) ssrc[base + i] = lds_s[i];
}

// ---------------------------------------------------------------------------
// GEMM1: h[N,64](bf16) = x[N,128] @ W[128,64]; as_/ad_ score dots.
// ---------------------------------------------------------------------------
__global__ __launch_bounds__(256) void gemm1_kernel(
    const float* __restrict__ x, const float* __restrict__ W,
    const void* __restrict__ a_src, const void* __restrict__ a_dst,
    const int* __restrict__ flags,
    u16* __restrict__ h, float* __restrict__ as_, float* __restrict__ ad_)
{
    __shared__ float xs[256 * 33];   // 33.8 KB
    __shared__ float Wl[32 * 64];    // 8 KB
    const int t = threadIdx.x;
    const int node0 = blockIdx.x * 256;
    const int bf = flags[0];
    const int ng = t >> 3;
    const int cg = t & 7;

    float acc[8][8];
    #pragma unroll
    for (int i = 0; i < 8; ++i)
        #pragma unroll
        for (int j = 0; j < 8; ++j) acc[i][j] = 0.f;

    for (int kc = 0; kc < 4; ++kc) {
        const int kb = kc * 32;
        const int c4 = t & 7;
        #pragma unroll
        for (int p = 0; p < 8; ++p) {
            int row = (t >> 3) + p * 32;
            int n = node0 + row;
            float4 vv = make_float4(0.f, 0.f, 0.f, 0.f);
            if (n < N_NODES) {
                if (!bf) {
                    vv = *(const float4*)(x + (size_t)n * 128 + kb + c4 * 4);
                } else {
                    const u16* xh = (const u16*)x;
                    vv.x = bf2f(xh[(size_t)n * 128 + kb + c4 * 4 + 0]);
                    vv.y = bf2f(xh[(size_t)n * 128 + kb + c4 * 4 + 1]);
                    vv.z = bf2f(xh[(size_t)n * 128 + kb + c4 * 4 + 2]);
                    vv.w = bf2f(xh[(size_t)n * 128 + kb + c4 * 4 + 3]);
                }
            }
            float* dstp = &xs[row * 33 + c4 * 4];
            dstp[0] = vv.x; dstp[1] = vv.y; dstp[2] = vv.z; dstp[3] = vv.w;
        }
        if (!bf) {
            #pragma unroll
            for (int qq = 0; qq < 2; ++qq) {
                int f4 = t * 2 + qq;
                ((float4*)Wl)[f4] = ((const float4*)(W + (size_t)kb * 64))[f4];
            }
        } else {
            const u16* Wh = (const u16*)W;
            for (int i = t; i < 2048; i += 256) Wl[i] = bf2f(Wh[(size_t)kb * 64 + i]);
        }
        __syncthreads();

        for (int kk = 0; kk < 32; ++kk) {
            float xr[8];
            #pragma unroll
            for (int i = 0; i < 8; ++i) xr[i] = xs[(ng * 8 + i) * 33 + kk];
            float4 w0 = *(const float4*)&Wl[kk * 64 + cg * 8];
            float4 w1 = *(const float4*)&Wl[kk * 64 + cg * 8 + 4];
            const float wr[8] = {w0.x, w0.y, w0.z, w0.w, w1.x, w1.y, w1.z, w1.w};
            #pragma unroll
            for (int i = 0; i < 8; ++i)
                #pragma unroll
                for (int j = 0; j < 8; ++j)
                    acc[i][j] = fmaf(xr[i], wr[j], acc[i][j]);
        }
        __syncthreads();
    }

    float av[8], dv[8];
    #pragma unroll
    for (int j = 0; j < 8; ++j) {
        av[j] = ldf(a_src, cg * 8 + j, bf);
        dv[j] = ldf(a_dst, cg * 8 + j, bf);
    }
    #pragma unroll
    for (int i = 0; i < 8; ++i) {
        int n = node0 + ng * 8 + i;
        float ps = 0.f, pd = 0.f;
        #pragma unroll
        for (int j = 0; j < 8; ++j) { ps += acc[i][j] * av[j]; pd += acc[i][j] * dv[j]; }
        #pragma unroll
        for (int off = 1; off < 8; off <<= 1) {
            ps += __shfl_xor(ps, off);
            pd += __shfl_xor(pd, off);
        }
        if (n < N_NODES) {
            uint4 hv;
            hv.x = (u32)f2bf(acc[i][0]) | ((u32)f2bf(acc[i][1]) << 16);
            hv.y = (u32)f2bf(acc[i][2]) | ((u32)f2bf(acc[i][3]) << 16);
            hv.z = (u32)f2bf(acc[i][4]) | ((u32)f2bf(acc[i][5]) << 16);
            hv.w = (u32)f2bf(acc[i][6]) | ((u32)f2bf(acc[i][7]) << 16);
            *(uint4*)&h[(size_t)n * 64 + cg * 8] = hv;
            if (cg == 0) { as_[n] = ps; ad_[n] = pd; }
        }
    }
}

// ---------------------------------------------------------------------------
// Score kernel (r6): one dst per THREAD. Batched 64-slot unrolled softmax
// (covers deg<=64, P~1; serial fallback beyond). Writes per-edge
// wexs[j] = { coef = exp(sc-m)/l  (f32 bits), src-row byte offset (src<<SH) }.
// This removes the 12-bpermute softmax chain + ~10 exps from every gather
// wave (the agg kernels were issue/latency-bound on that overhead:
// VALUBusy 63%, HBM 15%).
// ---------------------------------------------------------------------------
template<int SH>
__global__ __launch_bounds__(256) void score_kernel(
    const int* __restrict__ rowptr, const int* __restrict__ ssrc,
    const float* __restrict__ as_, const float* __restrict__ ad_,
    uint2* __restrict__ wexs)
{
    int d = blockIdx.x * 256 + threadIdx.x;
    if (d >= N_NODES) return;
    int beg = rowptr[d], end = rowptr[d + 1];
    int deg = end - beg;
    float add = ad_[d];

    if (deg <= 64) {
        int sj[64];
        float sc[64];
        #pragma unroll
        for (int i = 0; i < 64; ++i) {
            int j = beg + ((i < deg) ? i : 0);       // clamped, always valid
            sj[i] = ssrc[j];
        }
        #pragma unroll
        for (int i = 0; i < 64; ++i) sc[i] = as_[sj[i]];
        float m = -1e30f;
        #pragma unroll
        for (int i = 0; i < 64; ++i) {
            sc[i] = lrelu(sc[i] + add);
            m = (i < deg) ? fmaxf(m, sc[i]) : m;
        }
        float l = 0.f;
        #pragma unroll
        for (int i = 0; i < 64; ++i) {
            float e = (i < deg) ? __expf(sc[i] - m) : 0.f;
            sc[i] = e;
            l += e;
        }
        float inv = 1.f / l;
        #pragma unroll
        for (int i = 0; i < 64; ++i)
            if (i < deg)
                wexs[beg + i] = make_uint2(__float_as_uint(sc[i] * inv),
                                           ((u32)sj[i]) << SH);
    } else {
        // deg > 64: essentially never for this graph; correct serial path
        float m = -1e30f;
        for (int j = beg; j < end; ++j) m = fmaxf(m, lrelu(as_[ssrc[j]] + add));
        float l = 0.f;
        for (int j = beg; j < end; ++j) l += __expf(lrelu(as_[ssrc[j]] + add) - m);
        float inv = 1.f / l;
        for (int j = beg; j < end; ++j) {
            int s = ssrc[j];
            wexs[j] = make_uint2(
                __float_as_uint(__expf(lrelu(as_[s] + add) - m) * inv),
                ((u32)s) << SH);
        }
    }
}

// ---------------------------------------------------------------------------
// Gather, C=64 (r6): pure weighted gather, 2 dsts per wave (32 lanes each).
// 8 lanes/edge (uint4 = 16B of the 128B row), 4 edges/step, 8 unconditional
// steps cover deg<=32; wave-uniform extension loop beyond. No softmax, no
// bpermutes in the hot path (wexs read is a 8-lane L1 broadcast). Invalid
// edge slots clamp to edge 0's entry with weight forced to 0 (one cndmask).
// ---------------------------------------------------------------------------
__global__ __launch_bounds__(256) void gather64_kernel(
    const int* __restrict__ rowptr, const uint2* __restrict__ wexs,
    const u16* __restrict__ h, float* __restrict__ agg)
{
    const int tid = threadIdx.x;
    const int hl = tid & 31;                      // lane within half-wave
    const int dreal = blockIdx.x * 8 + (tid >> 5);
    const int dst = min(dreal, N_NODES - 1);
    const int beg = rowptr[dst];
    const int deg = rowptr[dst + 1] - beg;
    const int e4 = hl >> 3;                       // edge slot in group (0..3)
    const int i8 = hl & 7;                        // uint4 index in 128B row
    const char* __restrict__ hb = (const char*)h;
    const u32 boff = (u32)(i8 * 16);

    float acc[8] = {0.f, 0.f, 0.f, 0.f, 0.f, 0.f, 0.f, 0.f};

    #pragma unroll
    for (int g = 0; g < 8; ++g) {
        int eidx = g * 4 + e4;
        bool valid = eidx < deg;
        uint2 p = wexs[beg + (valid ? eidx : 0)];
        float w = valid ? __uint_as_float(p.x) : 0.f;
        uint4 qv = *(const uint4*)(hb + (size_t)(p.y + boff));
        fma8(w, qv, acc);
    }
    int mdeg = max(deg, __shfl_xor(deg, 32));     // wave-uniform
    for (int g = 8; g * 4 < mdeg; ++g) {          // rare (deg > 32)
        int eidx = g * 4 + e4;
        bool valid = eidx < deg;
        uint2 p = wexs[beg + (valid ? eidx : 0)];
        float w = valid ? __uint_as_float(p.x) : 0.f;
        uint4 qv = *(const uint4*)(hb + (size_t)(p.y + boff));
        fma8(w, qv, acc);
    }

    // reduce across 4 edge-slots (lane stride 8, stays within 32-lane half)
    #pragma unroll
    for (int c = 0; c < 8; ++c) {
        acc[c] += __shfl_xor(acc[c], 8);
        acc[c] += __shfl_xor(acc[c], 16);
    }
    if (e4 == 0 && dreal < N_NODES) {
        *(float4*)&agg[(size_t)dst * 64 + i8 * 8] =
            make_float4(acc[0], acc[1], acc[2], acc[3]);
        *(float4*)&agg[(size_t)dst * 64 + i8 * 8 + 4] =
            make_float4(acc[4], acc[5], acc[6], acc[7]);
    }
}

// ---------------------------------------------------------------------------
// Gather, C=32 (r6): 2 dsts/wave, 4 lanes/edge (uint4 = 16B of 64B row),
// 8 edges/step, 4 unconditional steps cover deg<=32. Fused bias +
// log_softmax over 4 lanes x 8 channels. Weights pre-normalized (coef=ex/l).
// ---------------------------------------------------------------------------
__global__ __launch_bounds__(256) void gather32_lsm_kernel(
    const int* __restrict__ rowptr, const uint2* __restrict__ wexs,
    const u16* __restrict__ h, const void* __restrict__ b2,
    const int* __restrict__ flags, float* __restrict__ out)
{
    const int tid = threadIdx.x;
    const int hl = tid & 31;
    const int dreal = blockIdx.x * 8 + (tid >> 5);
    const int dst = min(dreal, N_NODES - 1);
    const int beg = rowptr[dst];
    const int deg = rowptr[dst + 1] - beg;
    const int e8 = hl >> 2;                       // edge slot in group (0..7)
    const int i4 = hl & 3;                        // uint4 index in 64B row
    const int bf = flags[0];
    const char* __restrict__ hb = (const char*)h;
    const u32 boff = (u32)(i4 * 16);

    float acc[8] = {0.f, 0.f, 0.f, 0.f, 0.f, 0.f, 0.f, 0.f};

    #pragma unroll
    for (int g = 0; g < 4; ++g) {
        int eidx = g * 8 + e8;
        bool valid = eidx < deg;
        uint2 p = wexs[beg + (valid ? eidx : 0)];
        float w = valid ? __uint_as_float(p.x) : 0.f;
        uint4 qv = *(const uint4*)(hb + (size_t)(p.y + boff));
        fma8(w, qv, acc);
    }
    int mdeg = max(deg, __shfl_xor(deg, 32));
    for (int g = 4; g * 8 < mdeg; ++g) {          // rare (deg > 32)
        int eidx = g * 8 + e8;
        bool valid = eidx < deg;
        uint2 p = wexs[beg + (valid ? eidx : 0)];
        float w = valid ? __uint_as_float(p.x) : 0.f;
        uint4 qv = *(const uint4*)(hb + (size_t)(p.y + boff));
        fma8(w, qv, acc);
    }

    // reduce across 8 edge-slots (stride 4; stays within 32-lane half)
    #pragma unroll
    for (int c = 0; c < 8; ++c) {
        acc[c] += __shfl_xor(acc[c], 4);
        acc[c] += __shfl_xor(acc[c], 8);
        acc[c] += __shfl_xor(acc[c], 16);
    }

    // fused bias + log_softmax: quad lanes (i4) x 8 channels
    float v[8];
    #pragma unroll
    for (int c = 0; c < 8; ++c) v[c] = acc[c] + ldf(b2, i4 * 8 + c, bf);
    float mx = v[0];
    #pragma unroll
    for (int c = 1; c < 8; ++c) mx = fmaxf(mx, v[c]);
    mx = fmaxf(mx, __shfl_xor(mx, 1));
    mx = fmaxf(mx, __shfl_xor(mx, 2));
    float ss = 0.f;
    #pragma unroll
    for (int c = 0; c < 8; ++c) ss += __expf(v[c] - mx);
    ss += __shfl_xor(ss, 1);
    ss += __shfl_xor(ss, 2);
    float lg = mx + __logf(ss);
    if (e8 == 0 && dreal < N_NODES) {
        *(float4*)&out[(size_t)dst * 32 + i4 * 8] =
            make_float4(v[0] - lg, v[1] - lg, v[2] - lg, v[3] - lg);
        *(float4*)&out[(size_t)dst * 32 + i4 * 8 + 4] =
            make_float4(v[4] - lg, v[5] - lg, v[6] - lg, v[7] - lg);
    }
}

// ---------------------------------------------------------------------------
// GEMM2: hin = relu(agg1 + b1); h2[N,32](bf16) = hin @ W[64,32].
// 128-node tile, 256 threads, 4 nodes x 4 channels per thread.
// ---------------------------------------------------------------------------
#define G2_TILE 128

__global__ __launch_bounds__(256, 3) void gemm2_kernel(
    const float* __restrict__ agg1, const void* __restrict__ b1,
    const u32* __restrict__ W32, const void* __restrict__ a_src,
    const void* __restrict__ a_dst, const int* __restrict__ flags,
    u16* __restrict__ h, float* __restrict__ as_, float* __restrict__ ad_)
{
    __shared__ __align__(16) float Wl[64 * 32];        // 8 KB
    __shared__ __align__(16) float xs[G2_TILE * 68];   // 34.8 KB
    const int tid = threadIdx.x;
    const int node0 = blockIdx.x * G2_TILE;
    const int bf = flags[0];

    // stage W2 as f32
    if (bf) {
        for (int i = tid; i < 1024; i += 256) {
            u32 u = W32[i];
            *(float2*)&Wl[2 * i] = make_float2(__uint_as_float(u << 16),
                                               __uint_as_float(u & 0xFFFF0000u));
        }
    } else {
        for (int i = tid; i < 2048; i += 256) Wl[i] = __uint_as_float(W32[i]);
    }
    // stage hin = relu(agg1 + b1), float4-coalesced
    #pragma unroll
    for (int it = 0; it < 8; ++it) {
        int i = tid + it * 256;           // [0, 2048)
        int nl = i >> 4;                  // local node 0..127
        int k  = (i & 15) * 4;
        int n = node0 + nl;
        float4 v = make_float4(0.f, 0.f, 0.f, 0.f);
        if (n < N_NODES) v = *(const float4*)(agg1 + (size_t)n * 64 + k);
        v.x = fmaxf(v.x + ldf(b1, k + 0, bf), 0.f);
        v.y = fmaxf(v.y + ldf(b1, k + 1, bf), 0.f);
        v.z = fmaxf(v.z + ldf(b1, k + 2, bf), 0.f);
        v.w = fmaxf(v.w + ldf(b1, k + 3, bf), 0.f);
        *(float4*)&xs[nl * 68 + k] = v;
    }
    __syncthreads();

    const int ch0 = (tid & 7) * 4;        // 4 output channels
    const int nb0 = (tid >> 3) * 4;       // 4 local nodes
    float acc[4][4];
    #pragma unroll
    for (int j = 0; j < 4; ++j)
        #pragma unroll
        for (int c = 0; c < 4; ++c) acc[j][c] = 0.f;

    #pragma unroll 4
    for (int k0 = 0; k0 < 64; k0 += 4) {
        float4 xv0 = *(const float4*)&xs[(nb0 + 0) * 68 + k0];
        float4 xv1 = *(const float4*)&xs[(nb0 + 1) * 68 + k0];
        float4 xv2 = *(const float4*)&xs[(nb0 + 2) * 68 + k0];
        float4 xv3 = *(const float4*)&xs[(nb0 + 3) * 68 + k0];
        const float* xp[4] = { (const float*)&xv0, (const float*)&xv1,
                               (const float*)&xv2, (const float*)&xv3 };
        #pragma unroll
        for (int kk = 0; kk < 4; ++kk) {
            float4 w = *(const float4*)&Wl[(k0 + kk) * 32 + ch0];
            #pragma unroll
            for (int j = 0; j < 4; ++j) {
                float xvv = xp[j][kk];
                acc[j][0] = fmaf(xvv, w.x, acc[j][0]);
                acc[j][1] = fmaf(xvv, w.y, acc[j][1]);
                acc[j][2] = fmaf(xvv, w.z, acc[j][2]);
                acc[j][3] = fmaf(xvv, w.w, acc[j][3]);
            }
        }
    }

    float av[4], dv[4];
    #pragma unroll
    for (int c = 0; c < 4; ++c) {
        av[c] = ldf(a_src, ch0 + c, bf);
        dv[c] = ldf(a_dst, ch0 + c, bf);
    }
    #pragma unroll
    for (int j = 0; j < 4; ++j) {
        float ps = acc[j][0] * av[0] + acc[j][1] * av[1]
                 + acc[j][2] * av[2] + acc[j][3] * av[3];
        float pd = acc[j][0] * dv[0] + acc[j][1] * dv[1]
                 + acc[j][2] * dv[2] + acc[j][3] * dv[3];
        #pragma unroll
        for (int off = 1; off < 8; off <<= 1) {
            ps += __shfl_xor(ps, off);
            pd += __shfl_xor(pd, off);
        }
        int n = node0 + nb0 + j;
        if (n < N_NODES) {
            u32 p0 = (u32)f2bf(acc[j][0]) | ((u32)f2bf(acc[j][1]) << 16);
            u32 p1 = (u32)f2bf(acc[j][2]) | ((u32)f2bf(acc[j][3]) << 16);
            *(uint2*)&h[(size_t)n * 32 + ch0] = make_uint2(p0, p1);
            if ((tid & 7) == 0) { as_[n] = ps; ad_[n] = pd; }
        }
    }
}

// ---------------------------------------------------------------------------
extern "C" void kernel_launch(void* const* d_in, const int* in_sizes, int n_in,
                              void* d_out, int out_size, void* d_ws, size_t ws_size,
                              hipStream_t stream) {
    const float* x   = (const float*)d_in[0];
    const int* ei    = (const int*)d_in[1];
    const float* W1  = (const float*)d_in[2];
    const void* a_s1 = d_in[3];
    const void* a_d1 = d_in[4];
    const void* b1   = d_in[5];
    const u32* W2    = (const u32*)d_in[6];
    const void* a_s2 = d_in[7];
    const void* a_d2 = d_in[8];
    const void* b2   = d_in[9];
    float* out = (float*)d_out;

    // workspace carve-up (~61 MB). bbuf placed LAST so the 13.6-MB wexs
    // table can alias it (bbuf is dead after scatter_kernel).
    char* base = (char*)d_ws;
    int* flags = (int*)base;
    u16* h     = (u16*)(base + 64);                           // N*64 bf16 (reused N*32)
    char* q = base + 64 + (size_t)N_NODES * 64 * 2;
    float* as1 = (float*)q; q += (size_t)N_NODES * 4;
    float* ad1 = (float*)q; q += (size_t)N_NODES * 4;
    float* as2 = (float*)q; q += (size_t)N_NODES * 4;
    float* ad2 = (float*)q; q += (size_t)N_NODES * 4;
    float* agg1 = (float*)q; q += (size_t)N_NODES * 64 * 4;
    int* rowptr = (int*)q;  q += (size_t)(N_NODES + 16) * 4;
    int* ssrc   = (int*)q;  q += (size_t)ET * 4;
    int* bcnt   = (int*)q;  q += 256 * 4;
    int* bbase  = (int*)q;  q += 256 * 4;
    q = (char*)(((size_t)q + 255) & ~(size_t)255);            // align 256
    u32*  bbuf  = (u32*)q;                                    // 8.03 MB (dead after scatter)
    uint2* wexs = (uint2*)q;                                  // 13.6 MB, aliases bbuf

    detect_kernel<<<1, 64, 0, stream>>>((const u32*)x, ei, flags, bcnt);

    // CSR by dst via 2-pass bucket sort (rowptr built in scatter)
    bin_kernel<<<(ET + BINCH - 1) / BINCH, 256, 0, stream>>>(ei, flags, bcnt, bbuf);
    bscan_kernel<<<1, 256, 0, stream>>>(bcnt, bbase);
    scatter_kernel<<<NBUCK, 1024, 0, stream>>>(bcnt, bbase, bbuf, rowptr, ssrc);

    // layer 1: gemm -> per-edge coef precompute -> pure gather
    gemm1_kernel<<<(N_NODES + 255) / 256, 256, 0, stream>>>(x, W1, a_s1, a_d1, flags, h, as1, ad1);
    score_kernel<7><<<(N_NODES + 255) / 256, 256, 0, stream>>>(rowptr, ssrc, as1, ad1, wexs);
    gather64_kernel<<<(N_NODES + 7) / 8, 256, 0, stream>>>(rowptr, wexs, h, agg1);

    // layer 2 (lsm fused; writes d_out directly)
    gemm2_kernel<<<(N_NODES + G2_TILE - 1) / G2_TILE, 256, 0, stream>>>(agg1, b1, W2, a_s2, a_d2, flags, h, as2, ad2);
    score_kernel<6><<<(N_NODES + 255) / 256, 256, 0, stream>>>(rowptr, ssrc, as2, ad2, wexs);
    gather32_lsm_kernel<<<(N_NODES + 7) / 8, 256, 0, stream>>>(rowptr, wexs, h, b2, flags, out);
}

// Round 7
// 338.387 us; speedup vs baseline: 1.0261x; 1.0261x over previous
//
#include <hip/hip_runtime.h>

#define N_NODES 100000
#define N_EDGES 1600000
#define ET (N_EDGES + N_NODES)
#define NEG_SLOPE 0.2f

// bucket sort params
#define BSHIFT 9
#define BW 512                                  // nodes per bucket
#define NBUCK ((N_NODES + BW - 1) / BW)         // 196
#define BCAP 10240
#define BINCH 2048                              // edges per bin block

typedef unsigned short u16;
typedef unsigned int u32;

__device__ __forceinline__ float bf2f(u16 v) {
    return __uint_as_float(((u32)v) << 16);
}
__device__ __forceinline__ u16 f2bf(float f) {
    u32 u = __float_as_uint(f);
    u32 r = (u + 0x7FFFu + ((u >> 16) & 1u)) >> 16;  // RNE
    return (u16)r;
}
__device__ __forceinline__ float lrelu(float x) { return x > 0.f ? x : NEG_SLOPE * x; }
__device__ __forceinline__ float ldf(const void* p, int i, int bf) {
    return bf ? bf2f(((const u16*)p)[i]) : ((const float*)p)[i];
}
__device__ __forceinline__ int get_dst(const int* __restrict__ ei, int e, int ei64) {
    if (e < N_EDGES) return ei64 ? ei[2 * (N_EDGES + e)] : ei[N_EDGES + e];
    return e - N_EDGES;
}
__device__ __forceinline__ int get_src(const int* __restrict__ ei, int e, int ei64) {
    if (e < N_EDGES) return ei64 ? ei[2 * e] : ei[e];
    return e - N_EDGES;
}

// 8 bf16-channel FMA from one uint4 (16 B of an h row)
__device__ __forceinline__ void fma8(float wt, uint4 qv, float (&acc)[8]) {
    acc[0] = fmaf(wt, __uint_as_float(qv.x << 16), acc[0]);
    acc[1] = fmaf(wt, __uint_as_float(qv.x & 0xFFFF0000u), acc[1]);
    acc[2] = fmaf(wt, __uint_as_float(qv.y << 16), acc[2]);
    acc[3] = fmaf(wt, __uint_as_float(qv.y & 0xFFFF0000u), acc[3]);
    acc[4] = fmaf(wt, __uint_as_float(qv.z << 16), acc[4]);
    acc[5] = fmaf(wt, __uint_as_float(qv.z & 0xFFFF0000u), acc[5]);
    acc[6] = fmaf(wt, __uint_as_float(qv.w << 16), acc[6]);
    acc[7] = fmaf(wt, __uint_as_float(qv.w & 0xFFFF0000u), acc[7]);
}

// ---------------------------------------------------------------------------
// Detect input storage + zero bcnt (memset dispatch folded in).
// ---------------------------------------------------------------------------
__global__ void detect_kernel(const u32* __restrict__ x32, const int* __restrict__ ei,
                              int* __restrict__ flags, int* __restrict__ bcnt) {
    int lane = threadIdx.x;  // 64
    for (int i = lane; i < 256; i += 64) bcnt[i] = 0;
    u32 e = (x32[lane] >> 7) & 0xFFu;
    int ok = (e >= 96u && e <= 143u) ? 1 : 0;
    int cnt = (int)__popcll(__ballot(ok));
    int nz = (ei[2 * lane + 1] != 0) + (ei[2 * (lane + 64) + 1] != 0);
    #pragma unroll
    for (int off = 32; off > 0; off >>= 1) nz += __shfl_xor(nz, off);
    if (lane == 0) { flags[0] = (cnt >= 48) ? 1 : 0; flags[1] = (nz == 0) ? 1 : 0; }
}

// ---------------------------------------------------------------------------
// Pass 1: bin edges by dst>>9 into 196 buckets; code = (dst&511)<<17 | src.
// ---------------------------------------------------------------------------
__global__ __launch_bounds__(256) void bin_kernel(
    const int* __restrict__ ei, const int* __restrict__ flags,
    int* __restrict__ bcnt, u32* __restrict__ bbuf)
{
    __shared__ int hist[NBUCK];
    const int t = threadIdx.x;
    const int base = blockIdx.x * BINCH;
    const int ei64 = flags[1];
    for (int i = t; i < NBUCK; i += 256) hist[i] = 0;
    __syncthreads();
    for (int i = t; i < BINCH; i += 256) {
        int e = base + i;
        if (e >= ET) break;
        int d = get_dst(ei, e, ei64);
        atomicAdd(&hist[d >> BSHIFT], 1);
    }
    __syncthreads();
    for (int i = t; i < NBUCK; i += 256) {
        int c = hist[i];
        hist[i] = (c > 0) ? atomicAdd(&bcnt[i], c) : 0;
    }
    __syncthreads();
    for (int i = t; i < BINCH; i += 256) {
        int e = base + i;
        if (e >= ET) break;
        int d = get_dst(ei, e, ei64);
        int s = get_src(ei, e, ei64);
        int b = d >> BSHIFT;
        int pos = atomicAdd(&hist[b], 1);
        if (pos < BCAP)
            bbuf[(size_t)b * BCAP + pos] = ((u32)(d & (BW - 1)) << 17) | (u32)s;
    }
}

// exclusive scan of clamped bucket counts -> bbase[NBUCK+1]
__global__ __launch_bounds__(256) void bscan_kernel(
    const int* __restrict__ bcnt, int* __restrict__ bbase)
{
    __shared__ int sd[256];
    int t = threadIdx.x;
    int v = (t < NBUCK) ? min(bcnt[t], BCAP) : 0;
    sd[t] = v;
    __syncthreads();
    for (int off = 1; off < 256; off <<= 1) {
        int x = (t >= off) ? sd[t - off] : 0;
        __syncthreads();
        sd[t] += x;
        __syncthreads();
    }
    if (t < NBUCK) bbase[t] = sd[t] - v;
    if (t == NBUCK - 1) bbase[NBUCK] = sd[t];
}

// ---------------------------------------------------------------------------
// Pass 2: one block (1024 threads) per bucket -> rowptr + dst-sorted ssrc.
// ---------------------------------------------------------------------------
__global__ __launch_bounds__(1024) void scatter_kernel(
    const int* __restrict__ bcnt, const int* __restrict__ bbase,
    const u32* __restrict__ bbuf, int* __restrict__ rowptr, int* __restrict__ ssrc)
{
    __shared__ int hist[BW];
    __shared__ int cur[BW];
    __shared__ int wtot[4];
    __shared__ int lds_s[BCAP];
    const int t = threadIdx.x;
    const int b = blockIdx.x;
    const int cnt = min(bcnt[b], BCAP);
    const int base = bbase[b];
    const u32* mybuf = bbuf + (size_t)b * BCAP;

    if (t < BW) hist[t] = 0;
    __syncthreads();
    for (int i = t; i < cnt; i += 1024) atomicAdd(&hist[(int)(mybuf[i] >> 17)], 1);
    __syncthreads();
    int a0 = 0, a1 = 0, s = 0, v = 0;
    const int lane = t & 63, wid = t >> 6;
    if (t < 256) {
        a0 = hist[2 * t]; a1 = hist[2 * t + 1];
        s = a0 + a1;
        v = s;
        #pragma unroll
        for (int off = 1; off < 64; off <<= 1) {
            int n = __shfl_up(v, off);
            if (lane >= off) v += n;
        }
        if (lane == 63) wtot[wid] = v;
    }
    __syncthreads();
    if (t == 0) {
        int acc = 0;
        #pragma unroll
        for (int w = 0; w < 4; ++w) { int tmp = wtot[w]; wtot[w] = acc; acc += tmp; }
    }
    __syncthreads();
    if (t < 256) {
        int excl = v + wtot[wid] - s;
        cur[2 * t] = excl;
        cur[2 * t + 1] = excl + a0;
    }
    __syncthreads();
    if (t < BW) {
        int g = b * BW + t;
        if (g < N_NODES) rowptr[g] = base + cur[t];
    }
    if (b == NBUCK - 1 && t == 0) rowptr[N_NODES] = bbase[NBUCK];
    __syncthreads();
    for (int i = t; i < cnt; i += 1024) {
        u32 code = mybuf[i];
        int pos = atomicAdd(&cur[(int)(code >> 17)], 1);
        lds_s[pos] = (int)(code & 0x1FFFFu);
    }
    __syncthreads();
    for (int i = t; i < cnt; i += 1024) ssrc[base + i] = lds_s[i];
}

// ---------------------------------------------------------------------------
// GEMM1: h[N,64](bf16) = x[N,128] @ W[128,64]; as_/ad_ score dots.
// ---------------------------------------------------------------------------
__global__ __launch_bounds__(256) void gemm1_kernel(
    const float* __restrict__ x, const float* __restrict__ W,
    const void* __restrict__ a_src, const void* __restrict__ a_dst,
    const int* __restrict__ flags,
    u16* __restrict__ h, float* __restrict__ as_, float* __restrict__ ad_)
{
    __shared__ float xs[256 * 33];   // 33.8 KB
    __shared__ float Wl[32 * 64];    // 8 KB
    const int t = threadIdx.x;
    const int node0 = blockIdx.x * 256;
    const int bf = flags[0];
    const int ng = t >> 3;
    const int cg = t & 7;

    float acc[8][8];
    #pragma unroll
    for (int i = 0; i < 8; ++i)
        #pragma unroll
        for (int j = 0; j < 8; ++j) acc[i][j] = 0.f;

    for (int kc = 0; kc < 4; ++kc) {
        const int kb = kc * 32;
        const int c4 = t & 7;
        #pragma unroll
        for (int p = 0; p < 8; ++p) {
            int row = (t >> 3) + p * 32;
            int n = node0 + row;
            float4 vv = make_float4(0.f, 0.f, 0.f, 0.f);
            if (n < N_NODES) {
                if (!bf) {
                    vv = *(const float4*)(x + (size_t)n * 128 + kb + c4 * 4);
                } else {
                    const u16* xh = (const u16*)x;
                    vv.x = bf2f(xh[(size_t)n * 128 + kb + c4 * 4 + 0]);
                    vv.y = bf2f(xh[(size_t)n * 128 + kb + c4 * 4 + 1]);
                    vv.z = bf2f(xh[(size_t)n * 128 + kb + c4 * 4 + 2]);
                    vv.w = bf2f(xh[(size_t)n * 128 + kb + c4 * 4 + 3]);
                }
            }
            float* dstp = &xs[row * 33 + c4 * 4];
            dstp[0] = vv.x; dstp[1] = vv.y; dstp[2] = vv.z; dstp[3] = vv.w;
        }
        if (!bf) {
            #pragma unroll
            for (int qq = 0; qq < 2; ++qq) {
                int f4 = t * 2 + qq;
                ((float4*)Wl)[f4] = ((const float4*)(W + (size_t)kb * 64))[f4];
            }
        } else {
            const u16* Wh = (const u16*)W;
            for (int i = t; i < 2048; i += 256) Wl[i] = bf2f(Wh[(size_t)kb * 64 + i]);
        }
        __syncthreads();

        for (int kk = 0; kk < 32; ++kk) {
            float xr[8];
            #pragma unroll
            for (int i = 0; i < 8; ++i) xr[i] = xs[(ng * 8 + i) * 33 + kk];
            float4 w0 = *(const float4*)&Wl[kk * 64 + cg * 8];
            float4 w1 = *(const float4*)&Wl[kk * 64 + cg * 8 + 4];
            const float wr[8] = {w0.x, w0.y, w0.z, w0.w, w1.x, w1.y, w1.z, w1.w};
            #pragma unroll
            for (int i = 0; i < 8; ++i)
                #pragma unroll
                for (int j = 0; j < 8; ++j)
                    acc[i][j] = fmaf(xr[i], wr[j], acc[i][j]);
        }
        __syncthreads();
    }

    float av[8], dv[8];
    #pragma unroll
    for (int j = 0; j < 8; ++j) {
        av[j] = ldf(a_src, cg * 8 + j, bf);
        dv[j] = ldf(a_dst, cg * 8 + j, bf);
    }
    #pragma unroll
    for (int i = 0; i < 8; ++i) {
        int n = node0 + ng * 8 + i;
        float ps = 0.f, pd = 0.f;
        #pragma unroll
        for (int j = 0; j < 8; ++j) { ps += acc[i][j] * av[j]; pd += acc[i][j] * dv[j]; }
        #pragma unroll
        for (int off = 1; off < 8; off <<= 1) {
            ps += __shfl_xor(ps, off);
            pd += __shfl_xor(pd, off);
        }
        if (n < N_NODES) {
            uint4 hv;
            hv.x = (u32)f2bf(acc[i][0]) | ((u32)f2bf(acc[i][1]) << 16);
            hv.y = (u32)f2bf(acc[i][2]) | ((u32)f2bf(acc[i][3]) << 16);
            hv.z = (u32)f2bf(acc[i][4]) | ((u32)f2bf(acc[i][5]) << 16);
            hv.w = (u32)f2bf(acc[i][6]) | ((u32)f2bf(acc[i][7]) << 16);
            *(uint4*)&h[(size_t)n * 64 + cg * 8] = hv;
            if (cg == 0) { as_[n] = ps; ad_[n] = pd; }
        }
    }
}

// ---------------------------------------------------------------------------
// Score kernel (r7): WAVE per dst (4 dsts/block) — r6's thread-per-dst
// version held 128 VGPRs of unrolled state and issued 128 serial loads per
// thread (~40-55 us each). This is r5's proven softmax preamble as its own
// kernel: coalesced ssrc load, one as_ gather, 12-shfl reduce, coalesced
// uint2 store of {coef = ex/l, src<<SH}.
// ---------------------------------------------------------------------------
template<int SH>
__global__ __launch_bounds__(256) void score_kernel(
    const int* __restrict__ rowptr, const int* __restrict__ ssrc,
    const float* __restrict__ as_, const float* __restrict__ ad_,
    uint2* __restrict__ wexs)
{
    const int lane = threadIdx.x & 63;
    const int dst = blockIdx.x * 4 + (threadIdx.x >> 6);
    if (dst >= N_NODES) return;
    const int beg = rowptr[dst], end = rowptr[dst + 1];
    const int deg = end - beg;
    const float add = ad_[dst];

    if (deg <= 64) {
        int j = beg + lane;
        bool valid = j < end;
        int sj = valid ? ssrc[j] : 0;
        float sc = valid ? lrelu(as_[sj] + add) : -1e30f;
        float m = sc;
        #pragma unroll
        for (int off = 32; off > 0; off >>= 1) m = fmaxf(m, __shfl_xor(m, off));
        float ex = __expf(sc - m);                // invalid lanes underflow to 0
        float l = ex;
        #pragma unroll
        for (int off = 32; off > 0; off >>= 1) l += __shfl_xor(l, off);
        if (valid)
            wexs[j] = make_uint2(__float_as_uint(ex / l), ((u32)sj) << SH);
    } else {
        // deg > 64 (~never): 2-pass running softmax, then write pass
        float m = -1e30f, l = 0.f;
        for (int base = beg; base < end; base += 64) {
            int j = base + lane;
            bool valid = j < end;
            float sc = valid ? lrelu(as_[ssrc[j]] + add) : -1e30f;
            float cm = sc;
            #pragma unroll
            for (int off = 32; off > 0; off >>= 1) cm = fmaxf(cm, __shfl_xor(cm, off));
            float nm = fmaxf(m, cm);
            float cs = __expf(sc - nm);
            #pragma unroll
            for (int off = 32; off > 0; off >>= 1) cs += __shfl_xor(cs, off);
            l = l * __expf(m - nm) + cs;
            m = nm;
        }
        float inv = 1.f / l;
        for (int base = beg; base < end; base += 64) {
            int j = base + lane;
            if (j < end) {
                int sj = ssrc[j];
                wexs[j] = make_uint2(
                    __float_as_uint(__expf(lrelu(as_[sj] + add) - m) * inv),
                    ((u32)sj) << SH);
            }
        }
    }
}

// ---------------------------------------------------------------------------
// Gather, C=64 (r6): pure weighted gather, 2 dsts per wave (32 lanes each).
// 8 lanes/edge (uint4 = 16B of the 128B row), 4 edges/step, 8 unconditional
// steps cover deg<=32; wave-uniform extension loop beyond. Invalid edge
// slots clamp to edge 0's entry with weight forced to 0 (L1-hit re-read).
// ---------------------------------------------------------------------------
__global__ __launch_bounds__(256) void gather64_kernel(
    const int* __restrict__ rowptr, const uint2* __restrict__ wexs,
    const u16* __restrict__ h, float* __restrict__ agg)
{
    const int tid = threadIdx.x;
    const int hl = tid & 31;                      // lane within half-wave
    const int dreal = blockIdx.x * 8 + (tid >> 5);
    const int dst = min(dreal, N_NODES - 1);
    const int beg = rowptr[dst];
    const int deg = rowptr[dst + 1] - beg;
    const int e4 = hl >> 3;                       // edge slot in group (0..3)
    const int i8 = hl & 7;                        // uint4 index in 128B row
    const char* __restrict__ hb = (const char*)h;
    const u32 boff = (u32)(i8 * 16);

    float acc[8] = {0.f, 0.f, 0.f, 0.f, 0.f, 0.f, 0.f, 0.f};

    #pragma unroll
    for (int g = 0; g < 8; ++g) {
        int eidx = g * 4 + e4;
        bool valid = eidx < deg;
        uint2 p = wexs[beg + (valid ? eidx : 0)];
        float w = valid ? __uint_as_float(p.x) : 0.f;
        uint4 qv = *(const uint4*)(hb + (size_t)(p.y + boff));
        fma8(w, qv, acc);
    }
    int mdeg = max(deg, __shfl_xor(deg, 32));     // wave-uniform
    for (int g = 8; g * 4 < mdeg; ++g) {          // rare (deg > 32)
        int eidx = g * 4 + e4;
        bool valid = eidx < deg;
        uint2 p = wexs[beg + (valid ? eidx : 0)];
        float w = valid ? __uint_as_float(p.x) : 0.f;
        uint4 qv = *(const uint4*)(hb + (size_t)(p.y + boff));
        fma8(w, qv, acc);
    }

    // reduce across 4 edge-slots (lane stride 8, stays within 32-lane half)
    #pragma unroll
    for (int c = 0; c < 8; ++c) {
        acc[c] += __shfl_xor(acc[c], 8);
        acc[c] += __shfl_xor(acc[c], 16);
    }
    if (e4 == 0 && dreal < N_NODES) {
        *(float4*)&agg[(size_t)dst * 64 + i8 * 8] =
            make_float4(acc[0], acc[1], acc[2], acc[3]);
        *(float4*)&agg[(size_t)dst * 64 + i8 * 8 + 4] =
            make_float4(acc[4], acc[5], acc[6], acc[7]);
    }
}

// ---------------------------------------------------------------------------
// Gather, C=32 (r6): 2 dsts/wave, 4 lanes/edge (uint4 = 16B of 64B row),
// 8 edges/step, 4 unconditional steps cover deg<=32. Fused bias +
// log_softmax over 4 lanes x 8 channels. Weights pre-normalized (coef=ex/l).
// ---------------------------------------------------------------------------
__global__ __launch_bounds__(256) void gather32_lsm_kernel(
    const int* __restrict__ rowptr, const uint2* __restrict__ wexs,
    const u16* __restrict__ h, const void* __restrict__ b2,
    const int* __restrict__ flags, float* __restrict__ out)
{
    const int tid = threadIdx.x;
    const int hl = tid & 31;
    const int dreal = blockIdx.x * 8 + (tid >> 5);
    const int dst = min(dreal, N_NODES - 1);
    const int beg = rowptr[dst];
    const int deg = rowptr[dst + 1] - beg;
    const int e8 = hl >> 2;                       // edge slot in group (0..7)
    const int i4 = hl & 3;                        // uint4 index in 64B row
    const int bf = flags[0];
    const char* __restrict__ hb = (const char*)h;
    const u32 boff = (u32)(i4 * 16);

    float acc[8] = {0.f, 0.f, 0.f, 0.f, 0.f, 0.f, 0.f, 0.f};

    #pragma unroll
    for (int g = 0; g < 4; ++g) {
        int eidx = g * 8 + e8;
        bool valid = eidx < deg;
        uint2 p = wexs[beg + (valid ? eidx : 0)];
        float w = valid ? __uint_as_float(p.x) : 0.f;
        uint4 qv = *(const uint4*)(hb + (size_t)(p.y + boff));
        fma8(w, qv, acc);
    }
    int mdeg = max(deg, __shfl_xor(deg, 32));
    for (int g = 4; g * 8 < mdeg; ++g) {          // rare (deg > 32)
        int eidx = g * 8 + e8;
        bool valid = eidx < deg;
        uint2 p = wexs[beg + (valid ? eidx : 0)];
        float w = valid ? __uint_as_float(p.x) : 0.f;
        uint4 qv = *(const uint4*)(hb + (size_t)(p.y + boff));
        fma8(w, qv, acc);
    }

    // reduce across 8 edge-slots (stride 4; stays within 32-lane half)
    #pragma unroll
    for (int c = 0; c < 8; ++c) {
        acc[c] += __shfl_xor(acc[c], 4);
        acc[c] += __shfl_xor(acc[c], 8);
        acc[c] += __shfl_xor(acc[c], 16);
    }

    // fused bias + log_softmax: quad lanes (i4) x 8 channels
    float v[8];
    #pragma unroll
    for (int c = 0; c < 8; ++c) v[c] = acc[c] + ldf(b2, i4 * 8 + c, bf);
    float mx = v[0];
    #pragma unroll
    for (int c = 1; c < 8; ++c) mx = fmaxf(mx, v[c]);
    mx = fmaxf(mx, __shfl_xor(mx, 1));
    mx = fmaxf(mx, __shfl_xor(mx, 2));
    float ss = 0.f;
    #pragma unroll
    for (int c = 0; c < 8; ++c) ss += __expf(v[c] - mx);
    ss += __shfl_xor(ss, 1);
    ss += __shfl_xor(ss, 2);
    float lg = mx + __logf(ss);
    if (e8 == 0 && dreal < N_NODES) {
        *(float4*)&out[(size_t)dst * 32 + i4 * 8] =
            make_float4(v[0] - lg, v[1] - lg, v[2] - lg, v[3] - lg);
        *(float4*)&out[(size_t)dst * 32 + i4 * 8 + 4] =
            make_float4(v[4] - lg, v[5] - lg, v[6] - lg, v[7] - lg);
    }
}

// ---------------------------------------------------------------------------
// GEMM2: hin = relu(agg1 + b1); h2[N,32](bf16) = hin @ W[64,32].
// 128-node tile, 256 threads, 4 nodes x 4 channels per thread.
// ---------------------------------------------------------------------------
#define G2_TILE 128

__global__ __launch_bounds__(256, 3) void gemm2_kernel(
    const float* __restrict__ agg1, const void* __restrict__ b1,
    const u32* __restrict__ W32, const void* __restrict__ a_src,
    const void* __restrict__ a_dst, const int* __restrict__ flags,
    u16* __restrict__ h, float* __restrict__ as_, float* __restrict__ ad_)
{
    __shared__ __align__(16) float Wl[64 * 32];        // 8 KB
    __shared__ __align__(16) float xs[G2_TILE * 68];   // 34.8 KB
    const int tid = threadIdx.x;
    const int node0 = blockIdx.x * G2_TILE;
    const int bf = flags[0];

    // stage W2 as f32
    if (bf) {
        for (int i = tid; i < 1024; i += 256) {
            u32 u = W32[i];
            *(float2*)&Wl[2 * i] = make_float2(__uint_as_float(u << 16),
                                               __uint_as_float(u & 0xFFFF0000u));
        }
    } else {
        for (int i = tid; i < 2048; i += 256) Wl[i] = __uint_as_float(W32[i]);
    }
    // stage hin = relu(agg1 + b1), float4-coalesced
    #pragma unroll
    for (int it = 0; it < 8; ++it) {
        int i = tid + it * 256;           // [0, 2048)
        int nl = i >> 4;                  // local node 0..127
        int k  = (i & 15) * 4;
        int n = node0 + nl;
        float4 v = make_float4(0.f, 0.f, 0.f, 0.f);
        if (n < N_NODES) v = *(const float4*)(agg1 + (size_t)n * 64 + k);
        v.x = fmaxf(v.x + ldf(b1, k + 0, bf), 0.f);
        v.y = fmaxf(v.y + ldf(b1, k + 1, bf), 0.f);
        v.z = fmaxf(v.z + ldf(b1, k + 2, bf), 0.f);
        v.w = fmaxf(v.w + ldf(b1, k + 3, bf), 0.f);
        *(float4*)&xs[nl * 68 + k] = v;
    }
    __syncthreads();

    const int ch0 = (tid & 7) * 4;        // 4 output channels
    const int nb0 = (tid >> 3) * 4;       // 4 local nodes
    float acc[4][4];
    #pragma unroll
    for (int j = 0; j < 4; ++j)
        #pragma unroll
        for (int c = 0; c < 4; ++c) acc[j][c] = 0.f;

    #pragma unroll 4
    for (int k0 = 0; k0 < 64; k0 += 4) {
        float4 xv0 = *(const float4*)&xs[(nb0 + 0) * 68 + k0];
        float4 xv1 = *(const float4*)&xs[(nb0 + 1) * 68 + k0];
        float4 xv2 = *(const float4*)&xs[(nb0 + 2) * 68 + k0];
        float4 xv3 = *(const float4*)&xs[(nb0 + 3) * 68 + k0];
        const float* xp[4] = { (const float*)&xv0, (const float*)&xv1,
                               (const float*)&xv2, (const float*)&xv3 };
        #pragma unroll
        for (int kk = 0; kk < 4; ++kk) {
            float4 w = *(const float4*)&Wl[(k0 + kk) * 32 + ch0];
            #pragma unroll
            for (int j = 0; j < 4; ++j) {
                float xvv = xp[j][kk];
                acc[j][0] = fmaf(xvv, w.x, acc[j][0]);
                acc[j][1] = fmaf(xvv, w.y, acc[j][1]);
                acc[j][2] = fmaf(xvv, w.z, acc[j][2]);
                acc[j][3] = fmaf(xvv, w.w, acc[j][3]);
            }
        }
    }

    float av[4], dv[4];
    #pragma unroll
    for (int c = 0; c < 4; ++c) {
        av[c] = ldf(a_src, ch0 + c, bf);
        dv[c] = ldf(a_dst, ch0 + c, bf);
    }
    #pragma unroll
    for (int j = 0; j < 4; ++j) {
        float ps = acc[j][0] * av[0] + acc[j][1] * av[1]
                 + acc[j][2] * av[2] + acc[j][3] * av[3];
        float pd = acc[j][0] * dv[0] + acc[j][1] * dv[1]
                 + acc[j][2] * dv[2] + acc[j][3] * dv[3];
        #pragma unroll
        for (int off = 1; off < 8; off <<= 1) {
            ps += __shfl_xor(ps, off);
            pd += __shfl_xor(pd, off);
        }
        int n = node0 + nb0 + j;
        if (n < N_NODES) {
            u32 p0 = (u32)f2bf(acc[j][0]) | ((u32)f2bf(acc[j][1]) << 16);
            u32 p1 = (u32)f2bf(acc[j][2]) | ((u32)f2bf(acc[j][3]) << 16);
            *(uint2*)&h[(size_t)n * 32 + ch0] = make_uint2(p0, p1);
            if ((tid & 7) == 0) { as_[n] = ps; ad_[n] = pd; }
        }
    }
}

// ---------------------------------------------------------------------------
extern "C" void kernel_launch(void* const* d_in, const int* in_sizes, int n_in,
                              void* d_out, int out_size, void* d_ws, size_t ws_size,
                              hipStream_t stream) {
    const float* x   = (const float*)d_in[0];
    const int* ei    = (const int*)d_in[1];
    const float* W1  = (const float*)d_in[2];
    const void* a_s1 = d_in[3];
    const void* a_d1 = d_in[4];
    const void* b1   = d_in[5];
    const u32* W2    = (const u32*)d_in[6];
    const void* a_s2 = d_in[7];
    const void* a_d2 = d_in[8];
    const void* b2   = d_in[9];
    float* out = (float*)d_out;

    // workspace carve-up (~61 MB). bbuf placed LAST so the 13.6-MB wexs
    // table can alias it (bbuf is dead after scatter_kernel).
    char* base = (char*)d_ws;
    int* flags = (int*)base;
    u16* h     = (u16*)(base + 64);                           // N*64 bf16 (reused N*32)
    char* q = base + 64 + (size_t)N_NODES * 64 * 2;
    float* as1 = (float*)q; q += (size_t)N_NODES * 4;
    float* ad1 = (float*)q; q += (size_t)N_NODES * 4;
    float* as2 = (float*)q; q += (size_t)N_NODES * 4;
    float* ad2 = (float*)q; q += (size_t)N_NODES * 4;
    float* agg1 = (float*)q; q += (size_t)N_NODES * 64 * 4;
    int* rowptr = (int*)q;  q += (size_t)(N_NODES + 16) * 4;
    int* ssrc   = (int*)q;  q += (size_t)ET * 4;
    int* bcnt   = (int*)q;  q += 256 * 4;
    int* bbase  = (int*)q;  q += 256 * 4;
    q = (char*)(((size_t)q + 255) & ~(size_t)255);            // align 256
    u32*  bbuf  = (u32*)q;                                    // 8.03 MB (dead after scatter)
    uint2* wexs = (uint2*)q;                                  // 13.6 MB, aliases bbuf

    detect_kernel<<<1, 64, 0, stream>>>((const u32*)x, ei, flags, bcnt);

    // CSR by dst via 2-pass bucket sort (rowptr built in scatter)
    bin_kernel<<<(ET + BINCH - 1) / BINCH, 256, 0, stream>>>(ei, flags, bcnt, bbuf);
    bscan_kernel<<<1, 256, 0, stream>>>(bcnt, bbase);
    scatter_kernel<<<NBUCK, 1024, 0, stream>>>(bcnt, bbase, bbuf, rowptr, ssrc);

    // layer 1: gemm -> per-edge coef precompute -> pure gather
    gemm1_kernel<<<(N_NODES + 255) / 256, 256, 0, stream>>>(x, W1, a_s1, a_d1, flags, h, as1, ad1);
    score_kernel<7><<<(N_NODES + 3) / 4, 256, 0, stream>>>(rowptr, ssrc, as1, ad1, wexs);
    gather64_kernel<<<(N_NODES + 7) / 8, 256, 0, stream>>>(rowptr, wexs, h, agg1);

    // layer 2 (lsm fused; writes d_out directly)
    gemm2_kernel<<<(N_NODES + G2_TILE - 1) / G2_TILE, 256, 0, stream>>>(agg1, b1, W2, a_s2, a_d2, flags, h, as2, ad2);
    score_kernel<6><<<(N_NODES + 3) / 4, 256, 0, stream>>>(rowptr, ssrc, as2, ad2, wexs);
    gather32_lsm_kernel<<<(N_NODES + 7) / 8, 256, 0, stream>>>(rowptr, wexs, h, b2, flags, out);
}

// Round 8
// 331.532 us; speedup vs baseline: 1.0473x; 1.0207x over previous
//
#include <hip/hip_runtime.h>

#define N_NODES 100000
#define N_EDGES 1600000
#define ET (N_EDGES + N_NODES)
#define NEG_SLOPE 0.2f

// bucket sort params
#define BSHIFT 9
#define BW 512                                  // nodes per bucket
#define NBUCK ((N_NODES + BW - 1) / BW)         // 196
#define BCAP 10240
#define BINCH 2048                              // edges per bin block

typedef unsigned short u16;
typedef unsigned int u32;

__device__ __forceinline__ float bf2f(u16 v) {
    return __uint_as_float(((u32)v) << 16);
}
__device__ __forceinline__ u16 f2bf(float f) {
    u32 u = __float_as_uint(f);
    u32 r = (u + 0x7FFFu + ((u >> 16) & 1u)) >> 16;  // RNE
    return (u16)r;
}
__device__ __forceinline__ float lrelu(float x) { return x > 0.f ? x : NEG_SLOPE * x; }
__device__ __forceinline__ float ldf(const void* p, int i, int bf) {
    return bf ? bf2f(((const u16*)p)[i]) : ((const float*)p)[i];
}
__device__ __forceinline__ int get_dst(const int* __restrict__ ei, int e, int ei64) {
    if (e < N_EDGES) return ei64 ? ei[2 * (N_EDGES + e)] : ei[N_EDGES + e];
    return e - N_EDGES;
}
__device__ __forceinline__ int get_src(const int* __restrict__ ei, int e, int ei64) {
    if (e < N_EDGES) return ei64 ? ei[2 * e] : ei[e];
    return e - N_EDGES;
}

// 8 bf16-channel FMA from one uint4 (16 B of an h row)
__device__ __forceinline__ void fma8(float wt, uint4 qv, float (&acc)[8]) {
    acc[0] = fmaf(wt, __uint_as_float(qv.x << 16), acc[0]);
    acc[1] = fmaf(wt, __uint_as_float(qv.x & 0xFFFF0000u), acc[1]);
    acc[2] = fmaf(wt, __uint_as_float(qv.y << 16), acc[2]);
    acc[3] = fmaf(wt, __uint_as_float(qv.y & 0xFFFF0000u), acc[3]);
    acc[4] = fmaf(wt, __uint_as_float(qv.z << 16), acc[4]);
    acc[5] = fmaf(wt, __uint_as_float(qv.z & 0xFFFF0000u), acc[5]);
    acc[6] = fmaf(wt, __uint_as_float(qv.w << 16), acc[6]);
    acc[7] = fmaf(wt, __uint_as_float(qv.w & 0xFFFF0000u), acc[7]);
}

// ---------------------------------------------------------------------------
// Detect input storage + zero bcnt (memset dispatch folded in).
// ---------------------------------------------------------------------------
__global__ void detect_kernel(const u32* __restrict__ x32, const int* __restrict__ ei,
                              int* __restrict__ flags, int* __restrict__ bcnt) {
    int lane = threadIdx.x;  // 64
    for (int i = lane; i < 256; i += 64) bcnt[i] = 0;
    u32 e = (x32[lane] >> 7) & 0xFFu;
    int ok = (e >= 96u && e <= 143u) ? 1 : 0;
    int cnt = (int)__popcll(__ballot(ok));
    int nz = (ei[2 * lane + 1] != 0) + (ei[2 * (lane + 64) + 1] != 0);
    #pragma unroll
    for (int off = 32; off > 0; off >>= 1) nz += __shfl_xor(nz, off);
    if (lane == 0) { flags[0] = (cnt >= 48) ? 1 : 0; flags[1] = (nz == 0) ? 1 : 0; }
}

// ---------------------------------------------------------------------------
// Pass 1: bin edges by dst>>9 into 196 buckets; code = (dst&511)<<17 | src.
// r8: edges cached in registers (8/thread) -> single pass over ei.
// ---------------------------------------------------------------------------
__global__ __launch_bounds__(256) void bin_kernel(
    const int* __restrict__ ei, const int* __restrict__ flags,
    int* __restrict__ bcnt, u32* __restrict__ bbuf)
{
    __shared__ int hist[NBUCK];
    const int t = threadIdx.x;
    const int base = blockIdx.x * BINCH;
    const int ei64 = flags[1];
    for (int i = t; i < NBUCK; i += 256) hist[i] = 0;
    __syncthreads();

    int dloc[8], sloc[8];
    #pragma unroll
    for (int p = 0; p < 8; ++p) {
        int e = base + t + p * 256;
        if (e < ET) {
            dloc[p] = get_dst(ei, e, ei64);
            sloc[p] = get_src(ei, e, ei64);
            atomicAdd(&hist[dloc[p] >> BSHIFT], 1);
        } else {
            dloc[p] = -1; sloc[p] = 0;
        }
    }
    __syncthreads();
    for (int i = t; i < NBUCK; i += 256) {
        int c = hist[i];
        hist[i] = (c > 0) ? atomicAdd(&bcnt[i], c) : 0;
    }
    __syncthreads();
    #pragma unroll
    for (int p = 0; p < 8; ++p) {
        if (dloc[p] >= 0) {
            int b = dloc[p] >> BSHIFT;
            int pos = atomicAdd(&hist[b], 1);
            if (pos < BCAP)
                bbuf[(size_t)b * BCAP + pos] =
                    ((u32)(dloc[p] & (BW - 1)) << 17) | (u32)sloc[p];
        }
    }
}

// exclusive scan of clamped bucket counts -> bbase[NBUCK+1]
__global__ __launch_bounds__(256) void bscan_kernel(
    const int* __restrict__ bcnt, int* __restrict__ bbase)
{
    __shared__ int sd[256];
    int t = threadIdx.x;
    int v = (t < NBUCK) ? min(bcnt[t], BCAP) : 0;
    sd[t] = v;
    __syncthreads();
    for (int off = 1; off < 256; off <<= 1) {
        int x = (t >= off) ? sd[t - off] : 0;
        __syncthreads();
        sd[t] += x;
        __syncthreads();
    }
    if (t < NBUCK) bbase[t] = sd[t] - v;
    if (t == NBUCK - 1) bbase[NBUCK] = sd[t];
}

// ---------------------------------------------------------------------------
// Pass 2: one block (1024 threads) per bucket -> rowptr + dst-sorted ssrc.
// ---------------------------------------------------------------------------
__global__ __launch_bounds__(1024) void scatter_kernel(
    const int* __restrict__ bcnt, const int* __restrict__ bbase,
    const u32* __restrict__ bbuf, int* __restrict__ rowptr, int* __restrict__ ssrc)
{
    __shared__ int hist[BW];
    __shared__ int cur[BW];
    __shared__ int wtot[4];
    __shared__ int lds_s[BCAP];
    const int t = threadIdx.x;
    const int b = blockIdx.x;
    const int cnt = min(bcnt[b], BCAP);
    const int base = bbase[b];
    const u32* mybuf = bbuf + (size_t)b * BCAP;

    if (t < BW) hist[t] = 0;
    __syncthreads();
    for (int i = t; i < cnt; i += 1024) atomicAdd(&hist[(int)(mybuf[i] >> 17)], 1);
    __syncthreads();
    int a0 = 0, a1 = 0, s = 0, v = 0;
    const int lane = t & 63, wid = t >> 6;
    if (t < 256) {
        a0 = hist[2 * t]; a1 = hist[2 * t + 1];
        s = a0 + a1;
        v = s;
        #pragma unroll
        for (int off = 1; off < 64; off <<= 1) {
            int n = __shfl_up(v, off);
            if (lane >= off) v += n;
        }
        if (lane == 63) wtot[wid] = v;
    }
    __syncthreads();
    if (t == 0) {
        int acc = 0;
        #pragma unroll
        for (int w = 0; w < 4; ++w) { int tmp = wtot[w]; wtot[w] = acc; acc += tmp; }
    }
    __syncthreads();
    if (t < 256) {
        int excl = v + wtot[wid] - s;
        cur[2 * t] = excl;
        cur[2 * t + 1] = excl + a0;
    }
    __syncthreads();
    if (t < BW) {
        int g = b * BW + t;
        if (g < N_NODES) rowptr[g] = base + cur[t];
    }
    if (b == NBUCK - 1 && t == 0) rowptr[N_NODES] = bbase[NBUCK];
    __syncthreads();
    for (int i = t; i < cnt; i += 1024) {
        u32 code = mybuf[i];
        int pos = atomicAdd(&cur[(int)(code >> 17)], 1);
        lds_s[pos] = (int)(code & 0x1FFFFu);
    }
    __syncthreads();
    for (int i = t; i < cnt; i += 1024) ssrc[base + i] = lds_s[i];
}

// ---------------------------------------------------------------------------
// GEMM1: h[N,64](bf16) = x[N,128] @ W[128,64]; as_/ad_ score dots.
// ---------------------------------------------------------------------------
__global__ __launch_bounds__(256) void gemm1_kernel(
    const float* __restrict__ x, const float* __restrict__ W,
    const void* __restrict__ a_src, const void* __restrict__ a_dst,
    const int* __restrict__ flags,
    u16* __restrict__ h, float* __restrict__ as_, float* __restrict__ ad_)
{
    __shared__ float xs[256 * 33];   // 33.8 KB
    __shared__ float Wl[32 * 64];    // 8 KB
    const int t = threadIdx.x;
    const int node0 = blockIdx.x * 256;
    const int bf = flags[0];
    const int ng = t >> 3;
    const int cg = t & 7;

    float acc[8][8];
    #pragma unroll
    for (int i = 0; i < 8; ++i)
        #pragma unroll
        for (int j = 0; j < 8; ++j) acc[i][j] = 0.f;

    for (int kc = 0; kc < 4; ++kc) {
        const int kb = kc * 32;
        const int c4 = t & 7;
        #pragma unroll
        for (int p = 0; p < 8; ++p) {
            int row = (t >> 3) + p * 32;
            int n = node0 + row;
            float4 vv = make_float4(0.f, 0.f, 0.f, 0.f);
            if (n < N_NODES) {
                if (!bf) {
                    vv = *(const float4*)(x + (size_t)n * 128 + kb + c4 * 4);
                } else {
                    const u16* xh = (const u16*)x;
                    vv.x = bf2f(xh[(size_t)n * 128 + kb + c4 * 4 + 0]);
                    vv.y = bf2f(xh[(size_t)n * 128 + kb + c4 * 4 + 1]);
                    vv.z = bf2f(xh[(size_t)n * 128 + kb + c4 * 4 + 2]);
                    vv.w = bf2f(xh[(size_t)n * 128 + kb + c4 * 4 + 3]);
                }
            }
            float* dstp = &xs[row * 33 + c4 * 4];
            dstp[0] = vv.x; dstp[1] = vv.y; dstp[2] = vv.z; dstp[3] = vv.w;
        }
        if (!bf) {
            #pragma unroll
            for (int qq = 0; qq < 2; ++qq) {
                int f4 = t * 2 + qq;
                ((float4*)Wl)[f4] = ((const float4*)(W + (size_t)kb * 64))[f4];
            }
        } else {
            const u16* Wh = (const u16*)W;
            for (int i = t; i < 2048; i += 256) Wl[i] = bf2f(Wh[(size_t)kb * 64 + i]);
        }
        __syncthreads();

        for (int kk = 0; kk < 32; ++kk) {
            float xr[8];
            #pragma unroll
            for (int i = 0; i < 8; ++i) xr[i] = xs[(ng * 8 + i) * 33 + kk];
            float4 w0 = *(const float4*)&Wl[kk * 64 + cg * 8];
            float4 w1 = *(const float4*)&Wl[kk * 64 + cg * 8 + 4];
            const float wr[8] = {w0.x, w0.y, w0.z, w0.w, w1.x, w1.y, w1.z, w1.w};
            #pragma unroll
            for (int i = 0; i < 8; ++i)
                #pragma unroll
                for (int j = 0; j < 8; ++j)
                    acc[i][j] = fmaf(xr[i], wr[j], acc[i][j]);
        }
        __syncthreads();
    }

    float av[8], dv[8];
    #pragma unroll
    for (int j = 0; j < 8; ++j) {
        av[j] = ldf(a_src, cg * 8 + j, bf);
        dv[j] = ldf(a_dst, cg * 8 + j, bf);
    }
    #pragma unroll
    for (int i = 0; i < 8; ++i) {
        int n = node0 + ng * 8 + i;
        float ps = 0.f, pd = 0.f;
        #pragma unroll
        for (int j = 0; j < 8; ++j) { ps += acc[i][j] * av[j]; pd += acc[i][j] * dv[j]; }
        #pragma unroll
        for (int off = 1; off < 8; off <<= 1) {
            ps += __shfl_xor(ps, off);
            pd += __shfl_xor(pd, off);
        }
        if (n < N_NODES) {
            uint4 hv;
            hv.x = (u32)f2bf(acc[i][0]) | ((u32)f2bf(acc[i][1]) << 16);
            hv.y = (u32)f2bf(acc[i][2]) | ((u32)f2bf(acc[i][3]) << 16);
            hv.z = (u32)f2bf(acc[i][4]) | ((u32)f2bf(acc[i][5]) << 16);
            hv.w = (u32)f2bf(acc[i][6]) | ((u32)f2bf(acc[i][7]) << 16);
            *(uint4*)&h[(size_t)n * 64 + cg * 8] = hv;
            if (cg == 0) { as_[n] = ps; ad_[n] = pd; }
        }
    }
}

// ---------------------------------------------------------------------------
// Score kernel (r7): WAVE per dst (4 dsts/block). Coalesced ssrc load, one
// as_ gather, 12-shfl reduce, coalesced uint2 store of {coef=ex/l, src<<SH}.
// ---------------------------------------------------------------------------
template<int SH>
__global__ __launch_bounds__(256) void score_kernel(
    const int* __restrict__ rowptr, const int* __restrict__ ssrc,
    const float* __restrict__ as_, const float* __restrict__ ad_,
    uint2* __restrict__ wexs)
{
    const int lane = threadIdx.x & 63;
    const int dst = blockIdx.x * 4 + (threadIdx.x >> 6);
    if (dst >= N_NODES) return;
    const int beg = rowptr[dst], end = rowptr[dst + 1];
    const int deg = end - beg;
    const float add = ad_[dst];

    if (deg <= 64) {
        int j = beg + lane;
        bool valid = j < end;
        int sj = valid ? ssrc[j] : 0;
        float sc = valid ? lrelu(as_[sj] + add) : -1e30f;
        float m = sc;
        #pragma unroll
        for (int off = 32; off > 0; off >>= 1) m = fmaxf(m, __shfl_xor(m, off));
        float ex = __expf(sc - m);                // invalid lanes underflow to 0
        float l = ex;
        #pragma unroll
        for (int off = 32; off > 0; off >>= 1) l += __shfl_xor(l, off);
        if (valid)
            wexs[j] = make_uint2(__float_as_uint(ex / l), ((u32)sj) << SH);
    } else {
        // deg > 64 (~never): 2-pass running softmax, then write pass
        float m = -1e30f, l = 0.f;
        for (int base = beg; base < end; base += 64) {
            int j = base + lane;
            bool valid = j < end;
            float sc = valid ? lrelu(as_[ssrc[j]] + add) : -1e30f;
            float cm = sc;
            #pragma unroll
            for (int off = 32; off > 0; off >>= 1) cm = fmaxf(cm, __shfl_xor(cm, off));
            float nm = fmaxf(m, cm);
            float cs = __expf(sc - nm);
            #pragma unroll
            for (int off = 32; off > 0; off >>= 1) cs += __shfl_xor(cs, off);
            l = l * __expf(m - nm) + cs;
            m = nm;
        }
        float inv = 1.f / l;
        for (int base = beg; base < end; base += 64) {
            int j = base + lane;
            if (j < end) {
                int sj = ssrc[j];
                wexs[j] = make_uint2(
                    __float_as_uint(__expf(lrelu(as_[sj] + add) - m) * inv),
                    ((u32)sj) << SH);
            }
        }
    }
}

// ---------------------------------------------------------------------------
// Gather C=64 + FUSED GEMM2 (r8). Gather phase identical to r7's gather64
// (55.4 us, HBM 43%, VALU 27%, DS pipe idle). Epilogue computes
// hin = relu(agg + b1); h2 = hin @ W2[64,32] (bf16) + as2/ad2 dots —
// eliminating the 25.6MB agg1 write + 25.6MB read + the gemm2 dispatch.
// W2 staged TRANSPOSED in LDS (W2t[c][66] pad: 2-way banks = free, b64
// aligned); hin redistributed via 64-float wave-private LDS (broadcast
// reads). Epilogue rides the idle DS pipe.
// ---------------------------------------------------------------------------
__global__ __launch_bounds__(256) void gather64_g2_kernel(
    const int* __restrict__ rowptr, const uint2* __restrict__ wexs,
    const u16* __restrict__ h, const void* __restrict__ b1,
    const u32* __restrict__ W32, const void* __restrict__ a_src,
    const void* __restrict__ a_dst, const int* __restrict__ flags,
    u16* __restrict__ h2, float* __restrict__ as2, float* __restrict__ ad2)
{
    __shared__ float W2t[32 * 66];       // 8.4 KB, W2t[c*66+k] = W2[k][c]
    __shared__ float hin_lds[8 * 64];    // 2 KB, per half-wave hin
    const int tid = threadIdx.x;
    const int hl = tid & 31;                      // lane within half-wave
    const int dreal = blockIdx.x * 8 + (tid >> 5);
    const int dst = min(dreal, N_NODES - 1);
    const int bf = flags[0];

    // stage W2 transposed (f32)
    if (bf) {
        for (int i = tid; i < 1024; i += 256) {   // elements 2i, 2i+1 (same row k)
            u32 u = W32[i];
            int k = i >> 4;                       // (2i)>>5
            int c = (2 * i) & 31;
            W2t[c * 66 + k] = __uint_as_float(u << 16);
            W2t[(c + 1) * 66 + k] = __uint_as_float(u & 0xFFFF0000u);
        }
    } else {
        for (int i = tid; i < 2048; i += 256) {
            int k = i >> 5, c = i & 31;
            W2t[c * 66 + k] = __uint_as_float(W32[i]);
        }
    }
    __syncthreads();

    const int beg = rowptr[dst];
    const int deg = rowptr[dst + 1] - beg;
    const int e4 = hl >> 3;                       // edge slot in group (0..3)
    const int i8 = hl & 7;                        // uint4 index in 128B row
    const char* __restrict__ hb = (const char*)h;
    const u32 boff = (u32)(i8 * 16);

    float acc[8] = {0.f, 0.f, 0.f, 0.f, 0.f, 0.f, 0.f, 0.f};

    #pragma unroll
    for (int g = 0; g < 8; ++g) {
        int eidx = g * 4 + e4;
        bool valid = eidx < deg;
        uint2 p = wexs[beg + (valid ? eidx : 0)];
        float w = valid ? __uint_as_float(p.x) : 0.f;
        uint4 qv = *(const uint4*)(hb + (size_t)(p.y + boff));
        fma8(w, qv, acc);
    }
    int mdeg = max(deg, __shfl_xor(deg, 32));     // wave-uniform
    for (int g = 8; g * 4 < mdeg; ++g) {          // rare (deg > 32)
        int eidx = g * 4 + e4;
        bool valid = eidx < deg;
        uint2 p = wexs[beg + (valid ? eidx : 0)];
        float w = valid ? __uint_as_float(p.x) : 0.f;
        uint4 qv = *(const uint4*)(hb + (size_t)(p.y + boff));
        fma8(w, qv, acc);
    }

    // reduce across 4 edge-slots; every lane then holds channels (hl&7)*8..+7
    #pragma unroll
    for (int c = 0; c < 8; ++c) {
        acc[c] += __shfl_xor(acc[c], 8);
        acc[c] += __shfl_xor(acc[c], 16);
    }

    // ---- fused gemm2 epilogue ----
    float* hin_s = &hin_lds[(tid >> 5) * 64];     // per half-wave region
    if (hl < 8) {
        float4 v0, v1;
        v0.x = fmaxf(acc[0] + ldf(b1, hl * 8 + 0, bf), 0.f);
        v0.y = fmaxf(acc[1] + ldf(b1, hl * 8 + 1, bf), 0.f);
        v0.z = fmaxf(acc[2] + ldf(b1, hl * 8 + 2, bf), 0.f);
        v0.w = fmaxf(acc[3] + ldf(b1, hl * 8 + 3, bf), 0.f);
        v1.x = fmaxf(acc[4] + ldf(b1, hl * 8 + 4, bf), 0.f);
        v1.y = fmaxf(acc[5] + ldf(b1, hl * 8 + 5, bf), 0.f);
        v1.z = fmaxf(acc[6] + ldf(b1, hl * 8 + 6, bf), 0.f);
        v1.w = fmaxf(acc[7] + ldf(b1, hl * 8 + 7, bf), 0.f);
        *(float4*)&hin_s[hl * 8] = v0;
        *(float4*)&hin_s[hl * 8 + 4] = v1;
    }
    __builtin_amdgcn_wave_barrier();
    asm volatile("s_waitcnt lgkmcnt(0)" ::: "memory");

    // matvec: lane hl computes output channel hl. hin read = LDS broadcast;
    // W2t read = 2-way banks (free).
    float o = 0.f;
    #pragma unroll 8
    for (int k = 0; k < 64; k += 2) {
        float2 hv = *(const float2*)&hin_s[k];
        float2 wv = *(const float2*)&W2t[hl * 66 + k];
        o = fmaf(hv.x, wv.x, o);
        o = fmaf(hv.y, wv.y, o);
    }

    float ps = o * ldf(a_src, hl, bf);
    float pd = o * ldf(a_dst, hl, bf);
    #pragma unroll
    for (int off = 1; off < 32; off <<= 1) {
        ps += __shfl_xor(ps, off);
        pd += __shfl_xor(pd, off);
    }
    u32 hbits = (u32)f2bf(o);
    u32 other = (u32)__shfl_xor((int)hbits, 1);
    if (dreal < N_NODES) {
        if ((hl & 1) == 0)
            *((u32*)h2 + (size_t)dst * 16 + (hl >> 1)) = hbits | (other << 16);
        if (hl == 0) { as2[dst] = ps; ad2[dst] = pd; }
    }
    __builtin_amdgcn_wave_barrier();   // hin_s reads precede any reuse
}

// ---------------------------------------------------------------------------
// Gather, C=32 (r6): 2 dsts/wave, 4 lanes/edge (uint4 = 16B of 64B row),
// 8 edges/step, 4 unconditional steps cover deg<=32. Fused bias +
// log_softmax over 4 lanes x 8 channels. Weights pre-normalized (coef=ex/l).
// ---------------------------------------------------------------------------
__global__ __launch_bounds__(256) void gather32_lsm_kernel(
    const int* __restrict__ rowptr, const uint2* __restrict__ wexs,
    const u16* __restrict__ h, const void* __restrict__ b2,
    const int* __restrict__ flags, float* __restrict__ out)
{
    const int tid = threadIdx.x;
    const int hl = tid & 31;
    const int dreal = blockIdx.x * 8 + (tid >> 5);
    const int dst = min(dreal, N_NODES - 1);
    const int beg = rowptr[dst];
    const int deg = rowptr[dst + 1] - beg;
    const int e8 = hl >> 2;                       // edge slot in group (0..7)
    const int i4 = hl & 3;                        // uint4 index in 64B row
    const int bf = flags[0];
    const char* __restrict__ hb = (const char*)h;
    const u32 boff = (u32)(i4 * 16);

    float acc[8] = {0.f, 0.f, 0.f, 0.f, 0.f, 0.f, 0.f, 0.f};

    #pragma unroll
    for (int g = 0; g < 4; ++g) {
        int eidx = g * 8 + e8;
        bool valid = eidx < deg;
        uint2 p = wexs[beg + (valid ? eidx : 0)];
        float w = valid ? __uint_as_float(p.x) : 0.f;
        uint4 qv = *(const uint4*)(hb + (size_t)(p.y + boff));
        fma8(w, qv, acc);
    }
    int mdeg = max(deg, __shfl_xor(deg, 32));
    for (int g = 4; g * 8 < mdeg; ++g) {          // rare (deg > 32)
        int eidx = g * 8 + e8;
        bool valid = eidx < deg;
        uint2 p = wexs[beg + (valid ? eidx : 0)];
        float w = valid ? __uint_as_float(p.x) : 0.f;
        uint4 qv = *(const uint4*)(hb + (size_t)(p.y + boff));
        fma8(w, qv, acc);
    }

    // reduce across 8 edge-slots (stride 4; stays within 32-lane half)
    #pragma unroll
    for (int c = 0; c < 8; ++c) {
        acc[c] += __shfl_xor(acc[c], 4);
        acc[c] += __shfl_xor(acc[c], 8);
        acc[c] += __shfl_xor(acc[c], 16);
    }

    // fused bias + log_softmax: quad lanes (i4) x 8 channels
    float v[8];
    #pragma unroll
    for (int c = 0; c < 8; ++c) v[c] = acc[c] + ldf(b2, i4 * 8 + c, bf);
    float mx = v[0];
    #pragma unroll
    for (int c = 1; c < 8; ++c) mx = fmaxf(mx, v[c]);
    mx = fmaxf(mx, __shfl_xor(mx, 1));
    mx = fmaxf(mx, __shfl_xor(mx, 2));
    float ss = 0.f;
    #pragma unroll
    for (int c = 0; c < 8; ++c) ss += __expf(v[c] - mx);
    ss += __shfl_xor(ss, 1);
    ss += __shfl_xor(ss, 2);
    float lg = mx + __logf(ss);
    if (e8 == 0 && dreal < N_NODES) {
        *(float4*)&out[(size_t)dst * 32 + i4 * 8] =
            make_float4(v[0] - lg, v[1] - lg, v[2] - lg, v[3] - lg);
        *(float4*)&out[(size_t)dst * 32 + i4 * 8 + 4] =
            make_float4(v[4] - lg, v[5] - lg, v[6] - lg, v[7] - lg);
    }
}

// ---------------------------------------------------------------------------
extern "C" void kernel_launch(void* const* d_in, const int* in_sizes, int n_in,
                              void* d_out, int out_size, void* d_ws, size_t ws_size,
                              hipStream_t stream) {
    const float* x   = (const float*)d_in[0];
    const int* ei    = (const int*)d_in[1];
    const float* W1  = (const float*)d_in[2];
    const void* a_s1 = d_in[3];
    const void* a_d1 = d_in[4];
    const void* b1   = d_in[5];
    const u32* W2    = (const u32*)d_in[6];
    const void* a_s2 = d_in[7];
    const void* a_d2 = d_in[8];
    const void* b2   = d_in[9];
    float* out = (float*)d_out;

    // workspace carve-up (~61 MB). bbuf placed LAST so the 13.6-MB wexs
    // table can alias it (bbuf is dead after scatter_kernel). h2 (6.4MB)
    // lives in the old agg1 region (gemm2 is fused; agg1 no longer exists).
    char* base = (char*)d_ws;
    int* flags = (int*)base;
    u16* h     = (u16*)(base + 64);                           // N*64 bf16 (layer-1)
    char* q = base + 64 + (size_t)N_NODES * 64 * 2;
    float* as1 = (float*)q; q += (size_t)N_NODES * 4;
    float* ad1 = (float*)q; q += (size_t)N_NODES * 4;
    float* as2 = (float*)q; q += (size_t)N_NODES * 4;
    float* ad2 = (float*)q; q += (size_t)N_NODES * 4;
    u16* h2    = (u16*)q;   q += (size_t)N_NODES * 64 * 4;    // uses 6.4MB of 25.6MB
    int* rowptr = (int*)q;  q += (size_t)(N_NODES + 16) * 4;
    int* ssrc   = (int*)q;  q += (size_t)ET * 4;
    int* bcnt   = (int*)q;  q += 256 * 4;
    int* bbase  = (int*)q;  q += 256 * 4;
    q = (char*)(((size_t)q + 255) & ~(size_t)255);            // align 256
    u32*  bbuf  = (u32*)q;                                    // 8.03 MB (dead after scatter)
    uint2* wexs = (uint2*)q;                                  // 13.6 MB, aliases bbuf

    detect_kernel<<<1, 64, 0, stream>>>((const u32*)x, ei, flags, bcnt);

    // CSR by dst via 2-pass bucket sort (rowptr built in scatter)
    bin_kernel<<<(ET + BINCH - 1) / BINCH, 256, 0, stream>>>(ei, flags, bcnt, bbuf);
    bscan_kernel<<<1, 256, 0, stream>>>(bcnt, bbase);
    scatter_kernel<<<NBUCK, 1024, 0, stream>>>(bcnt, bbase, bbuf, rowptr, ssrc);

    // layer 1: gemm -> per-edge coef precompute -> gather with fused gemm2
    gemm1_kernel<<<(N_NODES + 255) / 256, 256, 0, stream>>>(x, W1, a_s1, a_d1, flags, h, as1, ad1);
    score_kernel<7><<<(N_NODES + 3) / 4, 256, 0, stream>>>(rowptr, ssrc, as1, ad1, wexs);
    gather64_g2_kernel<<<(N_NODES + 7) / 8, 256, 0, stream>>>(
        rowptr, wexs, h, b1, W2, a_s2, a_d2, flags, h2, as2, ad2);

    // layer 2 (lsm fused; writes d_out directly)
    score_kernel<6><<<(N_NODES + 3) / 4, 256, 0, stream>>>(rowptr, ssrc, as2, ad2, wexs);
    gather32_lsm_kernel<<<(N_NODES + 7) / 8, 256, 0, stream>>>(rowptr, wexs, h2, b2, flags, out);
}

// Round 9
// 301.860 us; speedup vs baseline: 1.1502x; 1.0983x over previous
//
#include <hip/hip_runtime.h>

#define N_NODES 100000
#define N_EDGES 1600000
#define ET (N_EDGES + N_NODES)
#define NEG_SLOPE 0.2f

// bucket sort params
#define BSHIFT 9
#define BW 512                                  // nodes per bucket
#define NBUCK ((N_NODES + BW - 1) / BW)         // 196
#define BCAP 10240
#define BINCH 2048                              // edges per bin block

typedef unsigned short u16;
typedef unsigned int u32;

__device__ __forceinline__ float bf2f(u16 v) {
    return __uint_as_float(((u32)v) << 16);
}
__device__ __forceinline__ u16 f2bf(float f) {
    u32 u = __float_as_uint(f);
    u32 r = (u + 0x7FFFu + ((u >> 16) & 1u)) >> 16;  // RNE
    return (u16)r;
}
__device__ __forceinline__ float lrelu(float x) { return x > 0.f ? x : NEG_SLOPE * x; }
__device__ __forceinline__ float ldf(const void* p, int i, int bf) {
    return bf ? bf2f(((const u16*)p)[i]) : ((const float*)p)[i];
}
__device__ __forceinline__ int get_dst(const int* __restrict__ ei, int e, int ei64) {
    if (e < N_EDGES) return ei64 ? ei[2 * (N_EDGES + e)] : ei[N_EDGES + e];
    return e - N_EDGES;
}
__device__ __forceinline__ int get_src(const int* __restrict__ ei, int e, int ei64) {
    if (e < N_EDGES) return ei64 ? ei[2 * e] : ei[e];
    return e - N_EDGES;
}

// 8 bf16-channel FMA from one uint4 (16 B of an h row)
__device__ __forceinline__ void fma8(float wt, uint4 qv, float (&acc)[8]) {
    acc[0] = fmaf(wt, __uint_as_float(qv.x << 16), acc[0]);
    acc[1] = fmaf(wt, __uint_as_float(qv.x & 0xFFFF0000u), acc[1]);
    acc[2] = fmaf(wt, __uint_as_float(qv.y << 16), acc[2]);
    acc[3] = fmaf(wt, __uint_as_float(qv.y & 0xFFFF0000u), acc[3]);
    acc[4] = fmaf(wt, __uint_as_float(qv.z << 16), acc[4]);
    acc[5] = fmaf(wt, __uint_as_float(qv.z & 0xFFFF0000u), acc[5]);
    acc[6] = fmaf(wt, __uint_as_float(qv.w << 16), acc[6]);
    acc[7] = fmaf(wt, __uint_as_float(qv.w & 0xFFFF0000u), acc[7]);
}

// ---------------------------------------------------------------------------
// Detect input storage + zero bcnt (memset dispatch folded in).
// ---------------------------------------------------------------------------
__global__ void detect_kernel(const u32* __restrict__ x32, const int* __restrict__ ei,
                              int* __restrict__ flags, int* __restrict__ bcnt) {
    int lane = threadIdx.x;  // 64
    for (int i = lane; i < 256; i += 64) bcnt[i] = 0;
    u32 e = (x32[lane] >> 7) & 0xFFu;
    int ok = (e >= 96u && e <= 143u) ? 1 : 0;
    int cnt = (int)__popcll(__ballot(ok));
    int nz = (ei[2 * lane + 1] != 0) + (ei[2 * (lane + 64) + 1] != 0);
    #pragma unroll
    for (int off = 32; off > 0; off >>= 1) nz += __shfl_xor(nz, off);
    if (lane == 0) { flags[0] = (cnt >= 48) ? 1 : 0; flags[1] = (nz == 0) ? 1 : 0; }
}

// ---------------------------------------------------------------------------
// Pass 1: bin edges by dst>>9 into 196 buckets; code = (dst&511)<<17 | src.
// r8: edges cached in registers (8/thread) -> single pass over ei.
// ---------------------------------------------------------------------------
__global__ __launch_bounds__(256) void bin_kernel(
    const int* __restrict__ ei, const int* __restrict__ flags,
    int* __restrict__ bcnt, u32* __restrict__ bbuf)
{
    __shared__ int hist[NBUCK];
    const int t = threadIdx.x;
    const int base = blockIdx.x * BINCH;
    const int ei64 = flags[1];
    for (int i = t; i < NBUCK; i += 256) hist[i] = 0;
    __syncthreads();

    int dloc[8], sloc[8];
    #pragma unroll
    for (int p = 0; p < 8; ++p) {
        int e = base + t + p * 256;
        if (e < ET) {
            dloc[p] = get_dst(ei, e, ei64);
            sloc[p] = get_src(ei, e, ei64);
            atomicAdd(&hist[dloc[p] >> BSHIFT], 1);
        } else {
            dloc[p] = -1; sloc[p] = 0;
        }
    }
    __syncthreads();
    for (int i = t; i < NBUCK; i += 256) {
        int c = hist[i];
        hist[i] = (c > 0) ? atomicAdd(&bcnt[i], c) : 0;
    }
    __syncthreads();
    #pragma unroll
    for (int p = 0; p < 8; ++p) {
        if (dloc[p] >= 0) {
            int b = dloc[p] >> BSHIFT;
            int pos = atomicAdd(&hist[b], 1);
            if (pos < BCAP)
                bbuf[(size_t)b * BCAP + pos] =
                    ((u32)(dloc[p] & (BW - 1)) << 17) | (u32)sloc[p];
        }
    }
}

// exclusive scan of clamped bucket counts -> bbase[NBUCK+1]
__global__ __launch_bounds__(256) void bscan_kernel(
    const int* __restrict__ bcnt, int* __restrict__ bbase)
{
    __shared__ int sd[256];
    int t = threadIdx.x;
    int v = (t < NBUCK) ? min(bcnt[t], BCAP) : 0;
    sd[t] = v;
    __syncthreads();
    for (int off = 1; off < 256; off <<= 1) {
        int x = (t >= off) ? sd[t - off] : 0;
        __syncthreads();
        sd[t] += x;
        __syncthreads();
    }
    if (t < NBUCK) bbase[t] = sd[t] - v;
    if (t == NBUCK - 1) bbase[NBUCK] = sd[t];
}

// ---------------------------------------------------------------------------
// Pass 2: one block (1024 threads) per bucket -> rowptr + dst-sorted ssrc.
// ---------------------------------------------------------------------------
__global__ __launch_bounds__(1024) void scatter_kernel(
    const int* __restrict__ bcnt, const int* __restrict__ bbase,
    const u32* __restrict__ bbuf, int* __restrict__ rowptr, int* __restrict__ ssrc)
{
    __shared__ int hist[BW];
    __shared__ int cur[BW];
    __shared__ int wtot[4];
    __shared__ int lds_s[BCAP];
    const int t = threadIdx.x;
    const int b = blockIdx.x;
    const int cnt = min(bcnt[b], BCAP);
    const int base = bbase[b];
    const u32* mybuf = bbuf + (size_t)b * BCAP;

    if (t < BW) hist[t] = 0;
    __syncthreads();
    for (int i = t; i < cnt; i += 1024) atomicAdd(&hist[(int)(mybuf[i] >> 17)], 1);
    __syncthreads();
    int a0 = 0, a1 = 0, s = 0, v = 0;
    const int lane = t & 63, wid = t >> 6;
    if (t < 256) {
        a0 = hist[2 * t]; a1 = hist[2 * t + 1];
        s = a0 + a1;
        v = s;
        #pragma unroll
        for (int off = 1; off < 64; off <<= 1) {
            int n = __shfl_up(v, off);
            if (lane >= off) v += n;
        }
        if (lane == 63) wtot[wid] = v;
    }
    __syncthreads();
    if (t == 0) {
        int acc = 0;
        #pragma unroll
        for (int w = 0; w < 4; ++w) { int tmp = wtot[w]; wtot[w] = acc; acc += tmp; }
    }
    __syncthreads();
    if (t < 256) {
        int excl = v + wtot[wid] - s;
        cur[2 * t] = excl;
        cur[2 * t + 1] = excl + a0;
    }
    __syncthreads();
    if (t < BW) {
        int g = b * BW + t;
        if (g < N_NODES) rowptr[g] = base + cur[t];
    }
    if (b == NBUCK - 1 && t == 0) rowptr[N_NODES] = bbase[NBUCK];
    __syncthreads();
    for (int i = t; i < cnt; i += 1024) {
        u32 code = mybuf[i];
        int pos = atomicAdd(&cur[(int)(code >> 17)], 1);
        lds_s[pos] = (int)(code & 0x1FFFFu);
    }
    __syncthreads();
    for (int i = t; i < cnt; i += 1024) ssrc[base + i] = lds_s[i];
}

// ---------------------------------------------------------------------------
// GEMM1: h[N,64](bf16) = x[N,128] @ W[128,64]; as_/ad_ score dots.
// ---------------------------------------------------------------------------
__global__ __launch_bounds__(256) void gemm1_kernel(
    const float* __restrict__ x, const float* __restrict__ W,
    const void* __restrict__ a_src, const void* __restrict__ a_dst,
    const int* __restrict__ flags,
    u16* __restrict__ h, float* __restrict__ as_, float* __restrict__ ad_)
{
    __shared__ float xs[256 * 33];   // 33.8 KB
    __shared__ float Wl[32 * 64];    // 8 KB
    const int t = threadIdx.x;
    const int node0 = blockIdx.x * 256;
    const int bf = flags[0];
    const int ng = t >> 3;
    const int cg = t & 7;

    float acc[8][8];
    #pragma unroll
    for (int i = 0; i < 8; ++i)
        #pragma unroll
        for (int j = 0; j < 8; ++j) acc[i][j] = 0.f;

    for (int kc = 0; kc < 4; ++kc) {
        const int kb = kc * 32;
        const int c4 = t & 7;
        #pragma unroll
        for (int p = 0; p < 8; ++p) {
            int row = (t >> 3) + p * 32;
            int n = node0 + row;
            float4 vv = make_float4(0.f, 0.f, 0.f, 0.f);
            if (n < N_NODES) {
                if (!bf) {
                    vv = *(const float4*)(x + (size_t)n * 128 + kb + c4 * 4);
                } else {
                    const u16* xh = (const u16*)x;
                    vv.x = bf2f(xh[(size_t)n * 128 + kb + c4 * 4 + 0]);
                    vv.y = bf2f(xh[(size_t)n * 128 + kb + c4 * 4 + 1]);
                    vv.z = bf2f(xh[(size_t)n * 128 + kb + c4 * 4 + 2]);
                    vv.w = bf2f(xh[(size_t)n * 128 + kb + c4 * 4 + 3]);
                }
            }
            float* dstp = &xs[row * 33 + c4 * 4];
            dstp[0] = vv.x; dstp[1] = vv.y; dstp[2] = vv.z; dstp[3] = vv.w;
        }
        if (!bf) {
            #pragma unroll
            for (int qq = 0; qq < 2; ++qq) {
                int f4 = t * 2 + qq;
                ((float4*)Wl)[f4] = ((const float4*)(W + (size_t)kb * 64))[f4];
            }
        } else {
            const u16* Wh = (const u16*)W;
            for (int i = t; i < 2048; i += 256) Wl[i] = bf2f(Wh[(size_t)kb * 64 + i]);
        }
        __syncthreads();

        for (int kk = 0; kk < 32; ++kk) {
            float xr[8];
            #pragma unroll
            for (int i = 0; i < 8; ++i) xr[i] = xs[(ng * 8 + i) * 33 + kk];
            float4 w0 = *(const float4*)&Wl[kk * 64 + cg * 8];
            float4 w1 = *(const float4*)&Wl[kk * 64 + cg * 8 + 4];
            const float wr[8] = {w0.x, w0.y, w0.z, w0.w, w1.x, w1.y, w1.z, w1.w};
            #pragma unroll
            for (int i = 0; i < 8; ++i)
                #pragma unroll
                for (int j = 0; j < 8; ++j)
                    acc[i][j] = fmaf(xr[i], wr[j], acc[i][j]);
        }
        __syncthreads();
    }

    float av[8], dv[8];
    #pragma unroll
    for (int j = 0; j < 8; ++j) {
        av[j] = ldf(a_src, cg * 8 + j, bf);
        dv[j] = ldf(a_dst, cg * 8 + j, bf);
    }
    #pragma unroll
    for (int i = 0; i < 8; ++i) {
        int n = node0 + ng * 8 + i;
        float ps = 0.f, pd = 0.f;
        #pragma unroll
        for (int j = 0; j < 8; ++j) { ps += acc[i][j] * av[j]; pd += acc[i][j] * dv[j]; }
        #pragma unroll
        for (int off = 1; off < 8; off <<= 1) {
            ps += __shfl_xor(ps, off);
            pd += __shfl_xor(pd, off);
        }
        if (n < N_NODES) {
            uint4 hv;
            hv.x = (u32)f2bf(acc[i][0]) | ((u32)f2bf(acc[i][1]) << 16);
            hv.y = (u32)f2bf(acc[i][2]) | ((u32)f2bf(acc[i][3]) << 16);
            hv.z = (u32)f2bf(acc[i][4]) | ((u32)f2bf(acc[i][5]) << 16);
            hv.w = (u32)f2bf(acc[i][6]) | ((u32)f2bf(acc[i][7]) << 16);
            *(uint4*)&h[(size_t)n * 64 + cg * 8] = hv;
            if (cg == 0) { as_[n] = ps; ad_[n] = pd; }
        }
    }
}

// ---------------------------------------------------------------------------
// Gather C=64 + integrated softmax + FUSED GEMM2 (r9).
// 2 dsts/wave (32-lane halves). Fast path deg<=32: single-pass half-wave
// softmax; {rowoff, coef} redistributed via __shfl (source lanes confined to
// the active half -> divergence-safe). rowoff shfls + h loads issued BEFORE
// the softmax chain (r5's latency-hiding pattern). Removes the score kernel,
// the 27MB wexs round-trip, and the ssrc re-read.
// Epilogue (r9 fix): W2 staged LINEAR [k][c] (conflict-free staging; per-k
// reads are 32 consecutive dwords = perfect banking), hin read as b128
// broadcast. r8's transposed-stride-66 epilogue cost 64 b64 DS ops + 1M
// staging conflicts (~+24us).
// ---------------------------------------------------------------------------
__global__ __launch_bounds__(256) void gather64_g2_kernel(
    const int* __restrict__ rowptr, const int* __restrict__ ssrc,
    const float* __restrict__ as_, const float* __restrict__ ad_,
    const u16* __restrict__ h, const void* __restrict__ b1,
    const u32* __restrict__ W32, const void* __restrict__ a_src2,
    const void* __restrict__ a_dst2, const int* __restrict__ flags,
    u16* __restrict__ h2, float* __restrict__ as2, float* __restrict__ ad2)
{
    __shared__ float W2s[64 * 32];       // 8 KB, row-major [k][c]
    __shared__ float hin_lds[8 * 64];    // 2 KB, per half-wave hin
    const int tid = threadIdx.x;
    const int hl = tid & 31;                      // lane within half-wave
    const int hbase = tid & 32;                   // absolute base lane of half
    const int dreal = blockIdx.x * 8 + (tid >> 5);
    const int dst = min(dreal, N_NODES - 1);
    const int bf = flags[0];

    // stage W2 linear f32 (coalesced, conflict-free)
    if (bf) {
        for (int i = tid; i < 1024; i += 256) {
            u32 u = W32[i];
            *(float2*)&W2s[2 * i] = make_float2(__uint_as_float(u << 16),
                                                __uint_as_float(u & 0xFFFF0000u));
        }
    } else {
        for (int i = tid; i < 2048; i += 256) W2s[i] = __uint_as_float(W32[i]);
    }
    __syncthreads();

    const int beg = rowptr[dst];
    const int end = rowptr[dst + 1];
    const int deg = end - beg;
    const float add = ad_[dst];
    const int e4 = hl >> 3;                       // edge slot in group (0..3)
    const int i8 = hl & 7;                        // uint4 index in 128B row
    const char* __restrict__ hb = (const char*)h;
    const u32 boff = (u32)(i8 * 16);

    float acc[8] = {0.f, 0.f, 0.f, 0.f, 0.f, 0.f, 0.f, 0.f};

    if (deg <= 32) {
        int j = beg + hl;
        bool valid = hl < deg;
        int sj = valid ? ssrc[j] : 0;
        float asv = as_[sj];
        int rowoff = sj << 7;
        // redistribute row offsets, issue h loads before softmax
        int ga[8];
        #pragma unroll
        for (int g = 0; g < 8; ++g) ga[g] = __shfl(rowoff, hbase + g * 4 + e4);
        uint4 q[8];
        #pragma unroll
        for (int g = 0; g < 8; ++g)
            q[g] = *(const uint4*)(hb + (size_t)((u32)ga[g] + boff));

        float sc = valid ? lrelu(asv + add) : -1e30f;
        float m = sc;
        #pragma unroll
        for (int off = 16; off > 0; off >>= 1) m = fmaxf(m, __shfl_xor(m, off));
        float ex = __expf(sc - m);                // invalid lanes underflow to 0
        float l = ex;
        #pragma unroll
        for (int off = 16; off > 0; off >>= 1) l += __shfl_xor(l, off);
        float coef = ex / l;

        float w[8];
        #pragma unroll
        for (int g = 0; g < 8; ++g) w[g] = __shfl(coef, hbase + g * 4 + e4);
        #pragma unroll
        for (int g = 0; g < 8; ++g) fma8(w[g], q[g], acc);
    } else {
        // rare (P ~ 1e-3): pass 1 running softmax over 32-edge blocks
        float m = -1e30f, l = 0.f;
        for (int base = beg; base < end; base += 32) {
            int j = base + hl;
            bool valid = j < end;
            float sc = valid ? lrelu(as_[ssrc[j]] + add) : -1e30f;
            float cm = sc;
            #pragma unroll
            for (int off = 16; off > 0; off >>= 1) cm = fmaxf(cm, __shfl_xor(cm, off));
            float nm = fmaxf(m, cm);
            float cs = __expf(sc - nm);
            #pragma unroll
            for (int off = 16; off > 0; off >>= 1) cs += __shfl_xor(cs, off);
            l = l * __expf(m - nm) + cs;
            m = nm;
        }
        float inv = 1.f / l;
        // pass 2: gather with final coefs
        for (int base = beg; base < end; base += 32) {
            int j = base + hl;
            bool valid = j < end;
            int sj = valid ? ssrc[j] : 0;
            int rowoff = sj << 7;
            int ga[8];
            #pragma unroll
            for (int g = 0; g < 8; ++g) ga[g] = __shfl(rowoff, hbase + g * 4 + e4);
            uint4 q[8];
            #pragma unroll
            for (int g = 0; g < 8; ++g)
                q[g] = *(const uint4*)(hb + (size_t)((u32)ga[g] + boff));
            float sc = valid ? lrelu(as_[sj] + add) : -1e30f;
            float coef = __expf(sc - m) * inv;    // 0 for invalid
            float w[8];
            #pragma unroll
            for (int g = 0; g < 8; ++g) w[g] = __shfl(coef, hbase + g * 4 + e4);
            #pragma unroll
            for (int g = 0; g < 8; ++g) fma8(w[g], q[g], acc);
        }
    }

    // reduce across 4 edge-slots; every lane then holds channels (hl&7)*8..+7
    #pragma unroll
    for (int c = 0; c < 8; ++c) {
        acc[c] += __shfl_xor(acc[c], 8);
        acc[c] += __shfl_xor(acc[c], 16);
    }

    // ---- fused gemm2 epilogue ----
    float* hin_s = &hin_lds[(tid >> 5) * 64];     // per half-wave region
    if (hl < 8) {
        float4 v0, v1;
        v0.x = fmaxf(acc[0] + ldf(b1, hl * 8 + 0, bf), 0.f);
        v0.y = fmaxf(acc[1] + ldf(b1, hl * 8 + 1, bf), 0.f);
        v0.z = fmaxf(acc[2] + ldf(b1, hl * 8 + 2, bf), 0.f);
        v0.w = fmaxf(acc[3] + ldf(b1, hl * 8 + 3, bf), 0.f);
        v1.x = fmaxf(acc[4] + ldf(b1, hl * 8 + 4, bf), 0.f);
        v1.y = fmaxf(acc[5] + ldf(b1, hl * 8 + 5, bf), 0.f);
        v1.z = fmaxf(acc[6] + ldf(b1, hl * 8 + 6, bf), 0.f);
        v1.w = fmaxf(acc[7] + ldf(b1, hl * 8 + 7, bf), 0.f);
        *(float4*)&hin_s[hl * 8] = v0;
        *(float4*)&hin_s[hl * 8 + 4] = v1;
    }
    __builtin_amdgcn_wave_barrier();
    asm volatile("s_waitcnt lgkmcnt(0)" ::: "memory");

    // matvec: lane hl = output channel. hin = b128 broadcast; W2s per-k reads
    // are 32 consecutive dwords across the half-wave (conflict-free).
    float o = 0.f;
    #pragma unroll 16
    for (int k = 0; k < 64; k += 4) {
        float4 hv = *(const float4*)&hin_s[k];
        o = fmaf(hv.x, W2s[(k + 0) * 32 + hl], o);
        o = fmaf(hv.y, W2s[(k + 1) * 32 + hl], o);
        o = fmaf(hv.z, W2s[(k + 2) * 32 + hl], o);
        o = fmaf(hv.w, W2s[(k + 3) * 32 + hl], o);
    }

    float ps = o * ldf(a_src2, hl, bf);
    float pd = o * ldf(a_dst2, hl, bf);
    #pragma unroll
    for (int off = 1; off < 32; off <<= 1) {
        ps += __shfl_xor(ps, off);
        pd += __shfl_xor(pd, off);
    }
    u32 hbits = (u32)f2bf(o);
    u32 other = (u32)__shfl_xor((int)hbits, 1);
    if (dreal < N_NODES) {
        if ((hl & 1) == 0)
            *((u32*)h2 + (size_t)dst * 16 + (hl >> 1)) = hbits | (other << 16);
        if (hl == 0) { as2[dst] = ps; ad2[dst] = pd; }
    }
    __builtin_amdgcn_wave_barrier();   // hin_s reads precede any reuse
}

// ---------------------------------------------------------------------------
// Gather C=32 + integrated softmax + fused bias/log_softmax (r9).
// 2 dsts/wave, 4 lanes/edge (uint4 = 16B of 64B row), 8-edge groups,
// 4 groups cover deg<=32 (fast path). Same shfl redistribution scheme.
// ---------------------------------------------------------------------------
__global__ __launch_bounds__(256) void gather32_lsm_kernel(
    const int* __restrict__ rowptr, const int* __restrict__ ssrc,
    const float* __restrict__ as_, const float* __restrict__ ad_,
    const u16* __restrict__ h, const void* __restrict__ b2,
    const int* __restrict__ flags, float* __restrict__ out)
{
    const int tid = threadIdx.x;
    const int hl = tid & 31;
    const int hbase = tid & 32;
    const int dreal = blockIdx.x * 8 + (tid >> 5);
    const int dst = min(dreal, N_NODES - 1);
    const int beg = rowptr[dst];
    const int end = rowptr[dst + 1];
    const int deg = end - beg;
    const float add = ad_[dst];
    const int e8 = hl >> 2;                       // edge slot in group (0..7)
    const int i4 = hl & 3;                        // uint4 index in 64B row
    const int bf = flags[0];
    const char* __restrict__ hb = (const char*)h;
    const u32 boff = (u32)(i4 * 16);

    float acc[8] = {0.f, 0.f, 0.f, 0.f, 0.f, 0.f, 0.f, 0.f};

    if (deg <= 32) {
        int j = beg + hl;
        bool valid = hl < deg;
        int sj = valid ? ssrc[j] : 0;
        float asv = as_[sj];
        int rowoff = sj << 6;
        int ga[4];
        #pragma unroll
        for (int g = 0; g < 4; ++g) ga[g] = __shfl(rowoff, hbase + g * 8 + e8);
        uint4 q[4];
        #pragma unroll
        for (int g = 0; g < 4; ++g)
            q[g] = *(const uint4*)(hb + (size_t)((u32)ga[g] + boff));

        float sc = valid ? lrelu(asv + add) : -1e30f;
        float m = sc;
        #pragma unroll
        for (int off = 16; off > 0; off >>= 1) m = fmaxf(m, __shfl_xor(m, off));
        float ex = __expf(sc - m);
        float l = ex;
        #pragma unroll
        for (int off = 16; off > 0; off >>= 1) l += __shfl_xor(l, off);
        float coef = ex / l;

        float w[4];
        #pragma unroll
        for (int g = 0; g < 4; ++g) w[g] = __shfl(coef, hbase + g * 8 + e8);
        #pragma unroll
        for (int g = 0; g < 4; ++g) fma8(w[g], q[g], acc);
    } else {
        float m = -1e30f, l = 0.f;
        for (int base = beg; base < end; base += 32) {
            int j = base + hl;
            bool valid = j < end;
            float sc = valid ? lrelu(as_[ssrc[j]] + add) : -1e30f;
            float cm = sc;
            #pragma unroll
            for (int off = 16; off > 0; off >>= 1) cm = fmaxf(cm, __shfl_xor(cm, off));
            float nm = fmaxf(m, cm);
            float cs = __expf(sc - nm);
            #pragma unroll
            for (int off = 16; off > 0; off >>= 1) cs += __shfl_xor(cs, off);
            l = l * __expf(m - nm) + cs;
            m = nm;
        }
        float inv = 1.f / l;
        for (int base = beg; base < end; base += 32) {
            int j = base + hl;
            bool valid = j < end;
            int sj = valid ? ssrc[j] : 0;
            int rowoff = sj << 6;
            int ga[4];
            #pragma unroll
            for (int g = 0; g < 4; ++g) ga[g] = __shfl(rowoff, hbase + g * 8 + e8);
            uint4 q[4];
            #pragma unroll
            for (int g = 0; g < 4; ++g)
                q[g] = *(const uint4*)(hb + (size_t)((u32)ga[g] + boff));
            float sc = valid ? lrelu(as_[sj] + add) : -1e30f;
            float coef = __expf(sc - m) * inv;
            float w[4];
            #pragma unroll
            for (int g = 0; g < 4; ++g) w[g] = __shfl(coef, hbase + g * 8 + e8);
            #pragma unroll
            for (int g = 0; g < 4; ++g) fma8(w[g], q[g], acc);
        }
    }

    // reduce across 8 edge-slots (stride 4; stays within 32-lane half)
    #pragma unroll
    for (int c = 0; c < 8; ++c) {
        acc[c] += __shfl_xor(acc[c], 4);
        acc[c] += __shfl_xor(acc[c], 8);
        acc[c] += __shfl_xor(acc[c], 16);
    }

    // fused bias + log_softmax: quad lanes (i4) x 8 channels
    float v[8];
    #pragma unroll
    for (int c = 0; c < 8; ++c) v[c] = acc[c] + ldf(b2, i4 * 8 + c, bf);
    float mx = v[0];
    #pragma unroll
    for (int c = 1; c < 8; ++c) mx = fmaxf(mx, v[c]);
    mx = fmaxf(mx, __shfl_xor(mx, 1));
    mx = fmaxf(mx, __shfl_xor(mx, 2));
    float ss = 0.f;
    #pragma unroll
    for (int c = 0; c < 8; ++c) ss += __expf(v[c] - mx);
    ss += __shfl_xor(ss, 1);
    ss += __shfl_xor(ss, 2);
    float lg = mx + __logf(ss);
    if (e8 == 0 && dreal < N_NODES) {
        *(float4*)&out[(size_t)dst * 32 + i4 * 8] =
            make_float4(v[0] - lg, v[1] - lg, v[2] - lg, v[3] - lg);
        *(float4*)&out[(size_t)dst * 32 + i4 * 8 + 4] =
            make_float4(v[4] - lg, v[5] - lg, v[6] - lg, v[7] - lg);
    }
}

// ---------------------------------------------------------------------------
extern "C" void kernel_launch(void* const* d_in, const int* in_sizes, int n_in,
                              void* d_out, int out_size, void* d_ws, size_t ws_size,
                              hipStream_t stream) {
    const float* x   = (const float*)d_in[0];
    const int* ei    = (const int*)d_in[1];
    const float* W1  = (const float*)d_in[2];
    const void* a_s1 = d_in[3];
    const void* a_d1 = d_in[4];
    const void* b1   = d_in[5];
    const u32* W2    = (const u32*)d_in[6];
    const void* a_s2 = d_in[7];
    const void* a_d2 = d_in[8];
    const void* b2   = d_in[9];
    float* out = (float*)d_out;

    // workspace carve-up (~47 MB). wexs is gone (softmax integrated).
    char* base = (char*)d_ws;
    int* flags = (int*)base;
    u16* h     = (u16*)(base + 64);                           // N*64 bf16 (layer-1)
    char* q = base + 64 + (size_t)N_NODES * 64 * 2;
    float* as1 = (float*)q; q += (size_t)N_NODES * 4;
    float* ad1 = (float*)q; q += (size_t)N_NODES * 4;
    float* as2 = (float*)q; q += (size_t)N_NODES * 4;
    float* ad2 = (float*)q; q += (size_t)N_NODES * 4;
    u16* h2    = (u16*)q;   q += (size_t)N_NODES * 32 * 2;    // N*32 bf16 (layer-2)
    int* rowptr = (int*)q;  q += (size_t)(N_NODES + 16) * 4;
    int* ssrc   = (int*)q;  q += (size_t)ET * 4;
    int* bcnt   = (int*)q;  q += 256 * 4;
    int* bbase  = (int*)q;  q += 256 * 4;
    q = (char*)(((size_t)q + 255) & ~(size_t)255);            // align 256
    u32*  bbuf  = (u32*)q;                                    // 8.03 MB (sort only)

    detect_kernel<<<1, 64, 0, stream>>>((const u32*)x, ei, flags, bcnt);

    // CSR by dst via 2-pass bucket sort (rowptr built in scatter)
    bin_kernel<<<(ET + BINCH - 1) / BINCH, 256, 0, stream>>>(ei, flags, bcnt, bbuf);
    bscan_kernel<<<1, 256, 0, stream>>>(bcnt, bbase);
    scatter_kernel<<<NBUCK, 1024, 0, stream>>>(bcnt, bbase, bbuf, rowptr, ssrc);

    // layer 1: gemm -> gather (integrated softmax) with fused gemm2
    gemm1_kernel<<<(N_NODES + 255) / 256, 256, 0, stream>>>(x, W1, a_s1, a_d1, flags, h, as1, ad1);
    gather64_g2_kernel<<<(N_NODES + 7) / 8, 256, 0, stream>>>(
        rowptr, ssrc, as1, ad1, h, b1, W2, a_s2, a_d2, flags, h2, as2, ad2);

    // layer 2 (integrated softmax; lsm fused; writes d_out directly)
    gather32_lsm_kernel<<<(N_NODES + 7) / 8, 256, 0, stream>>>(
        rowptr, ssrc, as2, ad2, h2, b2, flags, out);
}